// Round 1
// baseline (1214.095 us; speedup 1.0000x reference)
//
#include <hip/hip_runtime.h>
#include <cmath>

// ---------------- CSR build ----------------

__global__ void k_degrees(const int* __restrict__ src, const int* __restrict__ dst,
                          int* __restrict__ outd, int* __restrict__ ind, int E) {
    for (int i = blockIdx.x * blockDim.x + threadIdx.x; i < E; i += gridDim.x * blockDim.x) {
        atomicAdd(&outd[src[i]], 1);
        atomicAdd(&ind[dst[i]], 1);
    }
}

__global__ void k_norms(const int* __restrict__ outd, const int* __restrict__ ind,
                        float* __restrict__ nsrc, float* __restrict__ ndst, int n) {
    int i = blockIdx.x * blockDim.x + threadIdx.x;
    if (i < n) {
        int od = outd[i], id = ind[i];
        nsrc[i] = od > 0 ? rsqrtf((float)od) : 0.f;
        ndst[i] = id > 0 ? rsqrtf((float)id) : 0.f;
    }
}

// single-block exclusive scan of in-degrees -> rowptr[0..n], rowptr[n] = E
__global__ __launch_bounds__(1024) void k_scan(const int* __restrict__ deg,
                                               int* __restrict__ rowptr, int n) {
    __shared__ int buf[1024];
    int t = threadIdx.x;
    int chunk = (n + 1023) / 1024;
    int lo = t * chunk;
    int hi = lo + chunk; if (hi > n) hi = n;
    int s = 0;
    for (int i = lo; i < hi; i++) s += deg[i];
    buf[t] = s;
    __syncthreads();
    for (int off = 1; off < 1024; off <<= 1) {
        int v = buf[t];
        int add = (t >= off) ? buf[t - off] : 0;
        __syncthreads();
        buf[t] = v + add;
        __syncthreads();
    }
    int excl = (t == 0) ? 0 : buf[t - 1];
    for (int i = lo; i < hi; i++) { rowptr[i] = excl; excl += deg[i]; }
    if (t == 1023) rowptr[n] = buf[1023];
}

__global__ void k_fill(const int* __restrict__ src, const int* __restrict__ dst,
                       const int* __restrict__ rowptr, int* __restrict__ counter,
                       int* __restrict__ colidx, int E) {
    for (int i = blockIdx.x * blockDim.x + threadIdx.x; i < E; i += gridDim.x * blockDim.x) {
        int d = dst[i];
        int pos = rowptr[d] + atomicAdd(&counter[d], 1);
        colidx[pos] = src[i];
    }
}

// ---------------- GEMM: h = (x @ W) * nsrc[:,None] ----------------
// 128 rows/block, 256 threads, 8x(DOUT/16) register tile per thread.
// W staged transposed into LDS with XOR swizzle (<=2-way bank conflict on b128 reads).

template <int DOUT>
__global__ __launch_bounds__(256) void k_gemm_norm(const float* __restrict__ x,
                                                   const float* __restrict__ W,
                                                   const float* __restrict__ nsrc,
                                                   float* __restrict__ h, int nrows) {
    constexpr int CPT = DOUT / 16;   // cols per thread: 8 (DOUT=128) or 4 (DOUT=64)
    __shared__ float wt[DOUT * 128];

    // stage W[k][c] -> wt[c*128 + (k ^ swz(c))], swz(c) = ((c>>3)&7)<<2
    {
        const float4* W4 = (const float4*)W;
        for (int idx = threadIdx.x; idx < 128 * (DOUT / 4); idx += 256) {
            int k = idx / (DOUT / 4);
            int c4 = (idx % (DOUT / 4)) * 4;
            float4 w = W4[idx];
            const float* wf = (const float*)&w;
#pragma unroll
            for (int j = 0; j < 4; j++) {
                int c = c4 + j;
                int swz = ((c >> 3) & 7) << 2;
                wt[c * 128 + (k ^ swz)] = wf[j];
            }
        }
    }
    __syncthreads();

    int rg = threadIdx.x >> 4;    // 0..15 -> 8 rows each
    int cg = threadIdx.x & 15;    // 0..15 -> CPT cols each
    int r0 = blockIdx.x * 128 + rg * 8;
    int c0 = cg * CPT;

    const float* xp[8];
#pragma unroll
    for (int r = 0; r < 8; r++) {
        int row = r0 + r;
        if (row >= nrows) row = nrows - 1;   // clamp for safe loads; store is guarded
        xp[r] = x + (size_t)row * 128;
    }

    float acc[8][CPT];
#pragma unroll
    for (int r = 0; r < 8; r++)
#pragma unroll
        for (int c = 0; c < CPT; c++) acc[r][c] = 0.f;

    for (int k = 0; k < 128; k += 4) {
        float4 wv[CPT];
#pragma unroll
        for (int c = 0; c < CPT; c++) {
            int cc = c0 + c;
            int swz = ((cc >> 3) & 7) << 2;
            wv[c] = *(const float4*)&wt[cc * 128 + (k ^ swz)];
        }
#pragma unroll
        for (int r = 0; r < 8; r++) {
            float4 xv = *(const float4*)(xp[r] + k);
#pragma unroll
            for (int c = 0; c < CPT; c++) {
                acc[r][c] += xv.x * wv[c].x;
                acc[r][c] += xv.y * wv[c].y;
                acc[r][c] += xv.z * wv[c].z;
                acc[r][c] += xv.w * wv[c].w;
            }
        }
    }

#pragma unroll
    for (int r = 0; r < 8; r++) {
        int row = r0 + r;
        if (row < nrows) {
            float nm = nsrc[row];
#pragma unroll
            for (int c = 0; c < CPT; c += 4) {
                float4 v = make_float4(acc[r][c] * nm, acc[r][c + 1] * nm,
                                       acc[r][c + 2] * nm, acc[r][c + 3] * nm);
                *(float4*)&h[(size_t)row * DOUT + c0 + c] = v;
            }
        }
    }
}

// ---------------- aggregation: out[i] = act( (sum_{e: dst=i} h[src_e]) * ndst[i] + b ) ----
// blockDim = D threads; 4 edges in flight (thread groups), float4 per lane.

template <int D, bool ACT>
__global__ __launch_bounds__(D) void k_aggregate(const float* __restrict__ h,
                                                 const int* __restrict__ rowptr,
                                                 const int* __restrict__ colidx,
                                                 const float* __restrict__ ndst,
                                                 const float* __restrict__ bias,
                                                 float* __restrict__ out, int n) {
    constexpr int FB = D / 4;            // float4 feature blocks per row
    __shared__ float4 red[D];
    int t = threadIdx.x;
    int fb = t % FB;                     // which float4 of the row
    int g = t / FB;                      // edge-group 0..3
    const float4* h4 = (const float4*)h;

    for (int node = blockIdx.x; node < n; node += gridDim.x) {
        int beg = rowptr[node], end = rowptr[node + 1];
        float4 acc = make_float4(0.f, 0.f, 0.f, 0.f);
        for (int e = beg + g; e < end; e += 4) {
            int s = colidx[e];
            float4 v = h4[(size_t)s * FB + fb];
            acc.x += v.x; acc.y += v.y; acc.z += v.z; acc.w += v.w;
        }
        red[t] = acc;
        __syncthreads();
        if (t < FB) {
            float4 a = red[t], b1 = red[t + FB], b2 = red[t + 2 * FB], b3 = red[t + 3 * FB];
            float nd = ndst[node];
            float4 bv = ((const float4*)bias)[t];
            float4 v;
            v.x = (a.x + b1.x + b2.x + b3.x) * nd + bv.x;
            v.y = (a.y + b1.y + b2.y + b3.y) * nd + bv.y;
            v.z = (a.z + b1.z + b2.z + b3.z) * nd + bv.z;
            v.w = (a.w + b1.w + b2.w + b3.w) * nd + bv.w;
            if (ACT) {
                v.x = tanhf(v.x); v.y = tanhf(v.y);
                v.z = tanhf(v.z); v.w = tanhf(v.w);
            }
            ((float4*)out)[(size_t)node * FB + t] = v;
        }
        __syncthreads();
    }
}

// ---------------- host ----------------

extern "C" void kernel_launch(void* const* d_in, const int* in_sizes, int n_in,
                              void* d_out, int out_size, void* d_ws, size_t ws_size,
                              hipStream_t stream) {
    const float* features = (const float*)d_in[0];
    const int* edges      = (const int*)d_in[1];
    const float* W0 = (const float*)d_in[2]; const float* b0 = (const float*)d_in[3];
    const float* W1 = (const float*)d_in[4]; const float* b1 = (const float*)d_in[5];
    const float* W2 = (const float*)d_in[6]; const float* b2 = (const float*)d_in[7];
    const float* W3 = (const float*)d_in[8]; const float* b3 = (const float*)d_in[9];
    float* out = (float*)d_out;

    const int N = in_sizes[0] / 128;
    const int E = in_sizes[1] / 2;
    const int* src = edges;
    const int* dst = edges + E;

    char* p = (char*)d_ws;
    float* bufA   = (float*)p; p += (size_t)N * 128 * 4;
    float* bufB   = (float*)p; p += (size_t)N * 128 * 4;
    int*   rowptr = (int*)p;   p += (((size_t)(N + 1) * 4 + 15) / 16) * 16;
    int*   colidx = (int*)p;   p += (size_t)E * 4;
    int*   outd   = (int*)p;   p += (size_t)N * 4;
    int*   ind    = (int*)p;   p += (size_t)N * 4;
    int*   counter= (int*)p;   p += (size_t)N * 4;
    float* nsrc   = (float*)p; p += (size_t)N * 4;
    float* ndst   = (float*)p; p += (size_t)N * 4;

    // zero outd/ind/counter (contiguous)
    hipMemsetAsync(outd, 0, (size_t)3 * N * 4, stream);

    k_degrees<<<2048, 256, 0, stream>>>(src, dst, outd, ind, E);
    k_norms<<<(N + 255) / 256, 256, 0, stream>>>(outd, ind, nsrc, ndst, N);
    k_scan<<<1, 1024, 0, stream>>>(ind, rowptr, N);
    k_fill<<<2048, 256, 0, stream>>>(src, dst, rowptr, counter, colidx, E);

    int gblk = (N + 127) / 128;
    k_gemm_norm<128><<<gblk, 256, 0, stream>>>(features, W0, nsrc, bufA, N);
    k_aggregate<128, true><<<8192, 128, 0, stream>>>(bufA, rowptr, colidx, ndst, b0, bufB, N);
    k_gemm_norm<128><<<gblk, 256, 0, stream>>>(bufB, W1, nsrc, bufA, N);
    k_aggregate<128, true><<<8192, 128, 0, stream>>>(bufA, rowptr, colidx, ndst, b1, bufB, N);
    k_gemm_norm<128><<<gblk, 256, 0, stream>>>(bufB, W2, nsrc, bufA, N);
    k_aggregate<128, true><<<8192, 128, 0, stream>>>(bufA, rowptr, colidx, ndst, b2, bufB, N);
    k_gemm_norm<64><<<gblk, 256, 0, stream>>>(bufB, W3, nsrc, bufA, N);
    k_aggregate<64, false><<<8192, 64, 0, stream>>>(bufA, rowptr, colidx, ndst, b3, out, N);
}

// Round 2
// 1082.854 us; speedup vs baseline: 1.1212x; 1.1212x over previous
//
#include <hip/hip_runtime.h>
#include <cmath>

// ---------------- CSR build ----------------

__global__ void k_degrees(const int* __restrict__ src, const int* __restrict__ dst,
                          int* __restrict__ outd, int* __restrict__ ind, int E) {
    for (int i = blockIdx.x * blockDim.x + threadIdx.x; i < E; i += gridDim.x * blockDim.x) {
        atomicAdd(&outd[src[i]], 1);
        atomicAdd(&ind[dst[i]], 1);
    }
}

__global__ void k_norms(const int* __restrict__ outd, const int* __restrict__ ind,
                        float* __restrict__ nsrc, float* __restrict__ ndst, int n) {
    int i = blockIdx.x * blockDim.x + threadIdx.x;
    if (i < n) {
        int od = outd[i], id = ind[i];
        nsrc[i] = od > 0 ? rsqrtf((float)od) : 0.f;
        ndst[i] = id > 0 ? rsqrtf((float)id) : 0.f;
    }
}

// ---------------- device-wide exclusive scan (tile = 2048) ----------------
// R1: replaces single-block k_scan (165 us, serial+uncoalesced) with 3-phase scan.

constexpr int SCAN_TILE = 2048;

__global__ __launch_bounds__(256) void k_scan_partial(const int* __restrict__ deg,
                                                      int* __restrict__ tilesum, int n) {
    __shared__ int red[256];
    int base = blockIdx.x * SCAN_TILE;
    int s = 0;
    for (int i = threadIdx.x; i < SCAN_TILE; i += 256) {
        int idx = base + i;
        if (idx < n) s += deg[idx];
    }
    red[threadIdx.x] = s;
    __syncthreads();
    for (int off = 128; off > 0; off >>= 1) {
        if (threadIdx.x < off) red[threadIdx.x] += red[threadIdx.x + off];
        __syncthreads();
    }
    if (threadIdx.x == 0) tilesum[blockIdx.x] = red[0];
}

// single thread scans the ~49 tile sums in place; also writes rowptr[n] = total
__global__ void k_scan_tiles(int* __restrict__ tilesum, int* __restrict__ rowptr,
                             int numTiles, int n) {
    if (threadIdx.x == 0 && blockIdx.x == 0) {
        int acc = 0;
        for (int i = 0; i < numTiles; i++) { int v = tilesum[i]; tilesum[i] = acc; acc += v; }
        rowptr[n] = acc;
    }
}

__global__ __launch_bounds__(256) void k_scan_final(const int* __restrict__ deg,
                                                    const int* __restrict__ tilesum,
                                                    int* __restrict__ rowptr, int n) {
    __shared__ int red[256];
    int base = blockIdx.x * SCAN_TILE;
    int lo = base + threadIdx.x * 8;        // 8 contiguous ints/thread = 32B/lane coalesced
    int v[8]; int s = 0;
#pragma unroll
    for (int j = 0; j < 8; j++) {
        int idx = lo + j;
        v[j] = (idx < n) ? deg[idx] : 0;
        s += v[j];
    }
    red[threadIdx.x] = s;
    __syncthreads();
    for (int off = 1; off < 256; off <<= 1) {   // Hillis-Steele inclusive scan
        int x = red[threadIdx.x];
        int add = (threadIdx.x >= off) ? red[threadIdx.x - off] : 0;
        __syncthreads();
        red[threadIdx.x] = x + add;
        __syncthreads();
    }
    int excl = tilesum[blockIdx.x] + (threadIdx.x ? red[threadIdx.x - 1] : 0);
#pragma unroll
    for (int j = 0; j < 8; j++) {
        int idx = lo + j;
        if (idx < n) rowptr[idx] = excl;
        excl += v[j];
    }
}

__global__ void k_fill(const int* __restrict__ src, const int* __restrict__ dst,
                       const int* __restrict__ rowptr, int* __restrict__ counter,
                       int* __restrict__ colidx, int E) {
    for (int i = blockIdx.x * blockDim.x + threadIdx.x; i < E; i += gridDim.x * blockDim.x) {
        int d = dst[i];
        int pos = rowptr[d] + atomicAdd(&counter[d], 1);
        colidx[pos] = src[i];
    }
}

// ---------------- GEMM: h = (x @ W) * nsrc[:,None] ----------------

template <int DOUT>
__global__ __launch_bounds__(256) void k_gemm_norm(const float* __restrict__ x,
                                                   const float* __restrict__ W,
                                                   const float* __restrict__ nsrc,
                                                   float* __restrict__ h, int nrows) {
    constexpr int CPT = DOUT / 16;   // cols per thread
    __shared__ float wt[DOUT * 128];

    {
        const float4* W4 = (const float4*)W;
        for (int idx = threadIdx.x; idx < 128 * (DOUT / 4); idx += 256) {
            int k = idx / (DOUT / 4);
            int c4 = (idx % (DOUT / 4)) * 4;
            float4 w = W4[idx];
            const float* wf = (const float*)&w;
#pragma unroll
            for (int j = 0; j < 4; j++) {
                int c = c4 + j;
                int swz = ((c >> 3) & 7) << 2;
                wt[c * 128 + (k ^ swz)] = wf[j];
            }
        }
    }
    __syncthreads();

    int rg = threadIdx.x >> 4;
    int cg = threadIdx.x & 15;
    int r0 = blockIdx.x * 128 + rg * 8;
    int c0 = cg * CPT;

    const float* xp[8];
#pragma unroll
    for (int r = 0; r < 8; r++) {
        int row = r0 + r;
        if (row >= nrows) row = nrows - 1;
        xp[r] = x + (size_t)row * 128;
    }

    float acc[8][CPT];
#pragma unroll
    for (int r = 0; r < 8; r++)
#pragma unroll
        for (int c = 0; c < CPT; c++) acc[r][c] = 0.f;

    for (int k = 0; k < 128; k += 4) {
        float4 wv[CPT];
#pragma unroll
        for (int c = 0; c < CPT; c++) {
            int cc = c0 + c;
            int swz = ((cc >> 3) & 7) << 2;
            wv[c] = *(const float4*)&wt[cc * 128 + (k ^ swz)];
        }
#pragma unroll
        for (int r = 0; r < 8; r++) {
            float4 xv = *(const float4*)(xp[r] + k);
#pragma unroll
            for (int c = 0; c < CPT; c++) {
                acc[r][c] += xv.x * wv[c].x;
                acc[r][c] += xv.y * wv[c].y;
                acc[r][c] += xv.z * wv[c].z;
                acc[r][c] += xv.w * wv[c].w;
            }
        }
    }

#pragma unroll
    for (int r = 0; r < 8; r++) {
        int row = r0 + r;
        if (row < nrows) {
            float nm = nsrc[row];
#pragma unroll
            for (int c = 0; c < CPT; c += 4) {
                float4 v = make_float4(acc[r][c] * nm, acc[r][c + 1] * nm,
                                       acc[r][c + 2] * nm, acc[r][c + 3] * nm);
                *(float4*)&h[(size_t)row * DOUT + c0 + c] = v;
            }
        }
    }
}

// ---------------- aggregation ----------------

template <int D, bool ACT>
__global__ __launch_bounds__(D) void k_aggregate(const float* __restrict__ h,
                                                 const int* __restrict__ rowptr,
                                                 const int* __restrict__ colidx,
                                                 const float* __restrict__ ndst,
                                                 const float* __restrict__ bias,
                                                 float* __restrict__ out, int n) {
    constexpr int FB = D / 4;
    __shared__ float4 red[D];
    int t = threadIdx.x;
    int fb = t % FB;
    int g = t / FB;
    const float4* h4 = (const float4*)h;

    for (int node = blockIdx.x; node < n; node += gridDim.x) {
        int beg = rowptr[node], end = rowptr[node + 1];
        float4 acc = make_float4(0.f, 0.f, 0.f, 0.f);
        for (int e = beg + g; e < end; e += 4) {
            int s = colidx[e];
            float4 v = h4[(size_t)s * FB + fb];
            acc.x += v.x; acc.y += v.y; acc.z += v.z; acc.w += v.w;
        }
        red[t] = acc;
        __syncthreads();
        if (t < FB) {
            float4 a = red[t], b1 = red[t + FB], b2 = red[t + 2 * FB], b3 = red[t + 3 * FB];
            float nd = ndst[node];
            float4 bv = ((const float4*)bias)[t];
            float4 v;
            v.x = (a.x + b1.x + b2.x + b3.x) * nd + bv.x;
            v.y = (a.y + b1.y + b2.y + b3.y) * nd + bv.y;
            v.z = (a.z + b1.z + b2.z + b3.z) * nd + bv.z;
            v.w = (a.w + b1.w + b2.w + b3.w) * nd + bv.w;
            if (ACT) {
                v.x = tanhf(v.x); v.y = tanhf(v.y);
                v.z = tanhf(v.z); v.w = tanhf(v.w);
            }
            ((float4*)out)[(size_t)node * FB + t] = v;
        }
        __syncthreads();
    }
}

// ---------------- host ----------------

extern "C" void kernel_launch(void* const* d_in, const int* in_sizes, int n_in,
                              void* d_out, int out_size, void* d_ws, size_t ws_size,
                              hipStream_t stream) {
    const float* features = (const float*)d_in[0];
    const int* edges      = (const int*)d_in[1];
    const float* W0 = (const float*)d_in[2]; const float* b0 = (const float*)d_in[3];
    const float* W1 = (const float*)d_in[4]; const float* b1 = (const float*)d_in[5];
    const float* W2 = (const float*)d_in[6]; const float* b2 = (const float*)d_in[7];
    const float* W3 = (const float*)d_in[8]; const float* b3 = (const float*)d_in[9];
    float* out = (float*)d_out;

    const int N = in_sizes[0] / 128;
    const int E = in_sizes[1] / 2;
    const int* src = edges;
    const int* dst = edges + E;
    const int numTiles = (N + SCAN_TILE - 1) / SCAN_TILE;

    char* p = (char*)d_ws;
    float* bufA   = (float*)p; p += (size_t)N * 128 * 4;
    float* bufB   = (float*)p; p += (size_t)N * 128 * 4;
    int*   rowptr = (int*)p;   p += (((size_t)(N + 1) * 4 + 15) / 16) * 16;
    int*   colidx = (int*)p;   p += (size_t)E * 4;
    int*   outd   = (int*)p;   p += (size_t)N * 4;
    int*   ind    = (int*)p;   p += (size_t)N * 4;
    int*   counter= (int*)p;   p += (size_t)N * 4;
    float* nsrc   = (float*)p; p += (size_t)N * 4;
    float* ndst   = (float*)p; p += (size_t)N * 4;
    int*   tilesum= (int*)p;   p += (((size_t)(numTiles + 1) * 4 + 15) / 16) * 16;

    hipMemsetAsync(outd, 0, (size_t)3 * N * 4, stream);   // outd, ind, counter contiguous

    k_degrees<<<2048, 256, 0, stream>>>(src, dst, outd, ind, E);
    k_norms<<<(N + 255) / 256, 256, 0, stream>>>(outd, ind, nsrc, ndst, N);
    k_scan_partial<<<numTiles, 256, 0, stream>>>(ind, tilesum, N);
    k_scan_tiles<<<1, 64, 0, stream>>>(tilesum, rowptr, numTiles, N);
    k_scan_final<<<numTiles, 256, 0, stream>>>(ind, tilesum, rowptr, N);
    k_fill<<<2048, 256, 0, stream>>>(src, dst, rowptr, counter, colidx, E);

    int gblk = (N + 127) / 128;
    k_gemm_norm<128><<<gblk, 256, 0, stream>>>(features, W0, nsrc, bufA, N);
    k_aggregate<128, true><<<8192, 128, 0, stream>>>(bufA, rowptr, colidx, ndst, b0, bufB, N);
    k_gemm_norm<128><<<gblk, 256, 0, stream>>>(bufB, W1, nsrc, bufA, N);
    k_aggregate<128, true><<<8192, 128, 0, stream>>>(bufA, rowptr, colidx, ndst, b1, bufB, N);
    k_gemm_norm<128><<<gblk, 256, 0, stream>>>(bufB, W2, nsrc, bufA, N);
    k_aggregate<128, true><<<8192, 128, 0, stream>>>(bufA, rowptr, colidx, ndst, b2, bufB, N);
    k_gemm_norm<64><<<gblk, 256, 0, stream>>>(bufB, W3, nsrc, bufA, N);
    k_aggregate<64, false><<<8192, 64, 0, stream>>>(bufA, rowptr, colidx, ndst, b3, out, N);
}

// Round 3
// 1016.873 us; speedup vs baseline: 1.1939x; 1.0649x over previous
//
#include <hip/hip_runtime.h>
#include <cmath>

// ---------------- CSR build ----------------

__global__ void k_degrees(const int* __restrict__ src, const int* __restrict__ dst,
                          int* __restrict__ outd, int* __restrict__ ind, int E) {
    for (int i = blockIdx.x * blockDim.x + threadIdx.x; i < E; i += gridDim.x * blockDim.x) {
        atomicAdd(&outd[src[i]], 1);
        atomicAdd(&ind[dst[i]], 1);
    }
}

__global__ void k_norms(const int* __restrict__ outd, const int* __restrict__ ind,
                        float* __restrict__ nsrc, float* __restrict__ ndst, int n) {
    int i = blockIdx.x * blockDim.x + threadIdx.x;
    if (i < n) {
        int od = outd[i], id = ind[i];
        nsrc[i] = od > 0 ? rsqrtf((float)od) : 0.f;
        ndst[i] = id > 0 ? rsqrtf((float)id) : 0.f;
    }
}

// ---------------- device-wide exclusive scan (tile = 2048) ----------------

constexpr int SCAN_TILE = 2048;

__global__ __launch_bounds__(256) void k_scan_partial(const int* __restrict__ deg,
                                                      int* __restrict__ tilesum, int n) {
    __shared__ int red[256];
    int base = blockIdx.x * SCAN_TILE;
    int s = 0;
    for (int i = threadIdx.x; i < SCAN_TILE; i += 256) {
        int idx = base + i;
        if (idx < n) s += deg[idx];
    }
    red[threadIdx.x] = s;
    __syncthreads();
    for (int off = 128; off > 0; off >>= 1) {
        if (threadIdx.x < off) red[threadIdx.x] += red[threadIdx.x + off];
        __syncthreads();
    }
    if (threadIdx.x == 0) tilesum[blockIdx.x] = red[0];
}

__global__ void k_scan_tiles(int* __restrict__ tilesum, int* __restrict__ rowptr,
                             int numTiles, int n) {
    if (threadIdx.x == 0 && blockIdx.x == 0) {
        int acc = 0;
        for (int i = 0; i < numTiles; i++) { int v = tilesum[i]; tilesum[i] = acc; acc += v; }
        rowptr[n] = acc;
    }
}

__global__ __launch_bounds__(256) void k_scan_final(const int* __restrict__ deg,
                                                    const int* __restrict__ tilesum,
                                                    int* __restrict__ rowptr, int n) {
    __shared__ int red[256];
    int base = blockIdx.x * SCAN_TILE;
    int lo = base + threadIdx.x * 8;
    int v[8]; int s = 0;
#pragma unroll
    for (int j = 0; j < 8; j++) {
        int idx = lo + j;
        v[j] = (idx < n) ? deg[idx] : 0;
        s += v[j];
    }
    red[threadIdx.x] = s;
    __syncthreads();
    for (int off = 1; off < 256; off <<= 1) {
        int x = red[threadIdx.x];
        int add = (threadIdx.x >= off) ? red[threadIdx.x - off] : 0;
        __syncthreads();
        red[threadIdx.x] = x + add;
        __syncthreads();
    }
    int excl = tilesum[blockIdx.x] + (threadIdx.x ? red[threadIdx.x - 1] : 0);
#pragma unroll
    for (int j = 0; j < 8; j++) {
        int idx = lo + j;
        if (idx < n) rowptr[idx] = excl;
        excl += v[j];
    }
}

__global__ void k_fill(const int* __restrict__ src, const int* __restrict__ dst,
                       const int* __restrict__ rowptr, int* __restrict__ counter,
                       int* __restrict__ colidx, int E) {
    for (int i = blockIdx.x * blockDim.x + threadIdx.x; i < E; i += gridDim.x * blockDim.x) {
        int d = dst[i];
        int pos = rowptr[d] + atomicAdd(&counter[d], 1);
        colidx[pos] = src[i];
    }
}

// ---------------- GEMM: h = (x @ W) * nsrc[:,None] ----------------

template <int DOUT>
__global__ __launch_bounds__(256) void k_gemm_norm(const float* __restrict__ x,
                                                   const float* __restrict__ W,
                                                   const float* __restrict__ nsrc,
                                                   float* __restrict__ h, int nrows) {
    constexpr int CPT = DOUT / 16;
    __shared__ float wt[DOUT * 128];

    {
        const float4* W4 = (const float4*)W;
        for (int idx = threadIdx.x; idx < 128 * (DOUT / 4); idx += 256) {
            int k = idx / (DOUT / 4);
            int c4 = (idx % (DOUT / 4)) * 4;
            float4 w = W4[idx];
            const float* wf = (const float*)&w;
#pragma unroll
            for (int j = 0; j < 4; j++) {
                int c = c4 + j;
                int swz = ((c >> 3) & 7) << 2;
                wt[c * 128 + (k ^ swz)] = wf[j];
            }
        }
    }
    __syncthreads();

    int rg = threadIdx.x >> 4;
    int cg = threadIdx.x & 15;
    int r0 = blockIdx.x * 128 + rg * 8;
    int c0 = cg * CPT;

    const float* xp[8];
#pragma unroll
    for (int r = 0; r < 8; r++) {
        int row = r0 + r;
        if (row >= nrows) row = nrows - 1;
        xp[r] = x + (size_t)row * 128;
    }

    float acc[8][CPT];
#pragma unroll
    for (int r = 0; r < 8; r++)
#pragma unroll
        for (int c = 0; c < CPT; c++) acc[r][c] = 0.f;

    for (int k = 0; k < 128; k += 4) {
        float4 wv[CPT];
#pragma unroll
        for (int c = 0; c < CPT; c++) {
            int cc = c0 + c;
            int swz = ((cc >> 3) & 7) << 2;
            wv[c] = *(const float4*)&wt[cc * 128 + (k ^ swz)];
        }
#pragma unroll
        for (int r = 0; r < 8; r++) {
            float4 xv = *(const float4*)(xp[r] + k);
#pragma unroll
            for (int c = 0; c < CPT; c++) {
                acc[r][c] += xv.x * wv[c].x;
                acc[r][c] += xv.y * wv[c].y;
                acc[r][c] += xv.z * wv[c].z;
                acc[r][c] += xv.w * wv[c].w;
            }
        }
    }

#pragma unroll
    for (int r = 0; r < 8; r++) {
        int row = r0 + r;
        if (row < nrows) {
            float nm = nsrc[row];
#pragma unroll
            for (int c = 0; c < CPT; c += 4) {
                float4 v = make_float4(acc[r][c] * nm, acc[r][c + 1] * nm,
                                       acc[r][c + 2] * nm, acc[r][c + 3] * nm);
                *(float4*)&h[(size_t)row * DOUT + c0 + c] = v;
            }
        }
    }
}

// ---------------- aggregation: wave-per-node, no barriers, MLP=4 ----------------
// R2: replaces block-per-node + LDS + __syncthreads (latency-bound: VALUBusy 19%,
// hbm 39%) with one wave per node, G edges in flight, 4x-unrolled gathers.

template <int D, bool ACT>
__global__ __launch_bounds__(256) void k_aggregate(const float* __restrict__ h,
                                                   const int* __restrict__ rowptr,
                                                   const int* __restrict__ colidx,
                                                   const float* __restrict__ ndst,
                                                   const float* __restrict__ bias,
                                                   float* __restrict__ out, int n) {
    constexpr int FB = D / 4;       // float4 blocks per row (32 or 16)
    constexpr int G  = 64 / FB;     // edge groups per wave (2 or 4)
    int wid  = (blockIdx.x * 256 + threadIdx.x) >> 6;
    int lane = threadIdx.x & 63;
    int fb = lane & (FB - 1);
    int g  = lane / FB;
    int waveCount = gridDim.x * 4;
    const float4* h4 = (const float4*)h;

    for (int node = wid; node < n; node += waveCount) {
        int beg = rowptr[node], end = rowptr[node + 1];
        float4 a0 = {0, 0, 0, 0}, a1 = {0, 0, 0, 0}, a2 = {0, 0, 0, 0}, a3 = {0, 0, 0, 0};
        int e = beg + g;
        for (; e + 3 * G < end; e += 4 * G) {
            int s0 = colidx[e];
            int s1 = colidx[e + G];
            int s2 = colidx[e + 2 * G];
            int s3 = colidx[e + 3 * G];
            float4 v0 = h4[(size_t)s0 * FB + fb];
            float4 v1 = h4[(size_t)s1 * FB + fb];
            float4 v2 = h4[(size_t)s2 * FB + fb];
            float4 v3 = h4[(size_t)s3 * FB + fb];
            a0.x += v0.x; a0.y += v0.y; a0.z += v0.z; a0.w += v0.w;
            a1.x += v1.x; a1.y += v1.y; a1.z += v1.z; a1.w += v1.w;
            a2.x += v2.x; a2.y += v2.y; a2.z += v2.z; a2.w += v2.w;
            a3.x += v3.x; a3.y += v3.y; a3.z += v3.z; a3.w += v3.w;
        }
        for (; e < end; e += G) {
            int s = colidx[e];
            float4 v = h4[(size_t)s * FB + fb];
            a0.x += v.x; a0.y += v.y; a0.z += v.z; a0.w += v.w;
        }
        float4 acc;
        acc.x = (a0.x + a1.x) + (a2.x + a3.x);
        acc.y = (a0.y + a1.y) + (a2.y + a3.y);
        acc.z = (a0.z + a1.z) + (a2.z + a3.z);
        acc.w = (a0.w + a1.w) + (a2.w + a3.w);
#pragma unroll
        for (int off = FB; off < 64; off <<= 1) {
            acc.x += __shfl_xor(acc.x, off);
            acc.y += __shfl_xor(acc.y, off);
            acc.z += __shfl_xor(acc.z, off);
            acc.w += __shfl_xor(acc.w, off);
        }
        if (g == 0) {
            float nd = ndst[node];
            float4 bv = ((const float4*)bias)[fb];
            float4 v;
            v.x = acc.x * nd + bv.x;
            v.y = acc.y * nd + bv.y;
            v.z = acc.z * nd + bv.z;
            v.w = acc.w * nd + bv.w;
            if (ACT) {
                v.x = tanhf(v.x); v.y = tanhf(v.y);
                v.z = tanhf(v.z); v.w = tanhf(v.w);
            }
            ((float4*)out)[(size_t)node * FB + fb] = v;
        }
    }
}

// ---------------- host ----------------

extern "C" void kernel_launch(void* const* d_in, const int* in_sizes, int n_in,
                              void* d_out, int out_size, void* d_ws, size_t ws_size,
                              hipStream_t stream) {
    const float* features = (const float*)d_in[0];
    const int* edges      = (const int*)d_in[1];
    const float* W0 = (const float*)d_in[2]; const float* b0 = (const float*)d_in[3];
    const float* W1 = (const float*)d_in[4]; const float* b1 = (const float*)d_in[5];
    const float* W2 = (const float*)d_in[6]; const float* b2 = (const float*)d_in[7];
    const float* W3 = (const float*)d_in[8]; const float* b3 = (const float*)d_in[9];
    float* out = (float*)d_out;

    const int N = in_sizes[0] / 128;
    const int E = in_sizes[1] / 2;
    const int* src = edges;
    const int* dst = edges + E;
    const int numTiles = (N + SCAN_TILE - 1) / SCAN_TILE;

    char* p = (char*)d_ws;
    float* bufA   = (float*)p; p += (size_t)N * 128 * 4;
    float* bufB   = (float*)p; p += (size_t)N * 128 * 4;
    int*   rowptr = (int*)p;   p += (((size_t)(N + 1) * 4 + 15) / 16) * 16;
    int*   colidx = (int*)p;   p += (size_t)E * 4;
    int*   outd   = (int*)p;   p += (size_t)N * 4;
    int*   ind    = (int*)p;   p += (size_t)N * 4;
    int*   counter= (int*)p;   p += (size_t)N * 4;
    float* nsrc   = (float*)p; p += (size_t)N * 4;
    float* ndst   = (float*)p; p += (size_t)N * 4;
    int*   tilesum= (int*)p;   p += (((size_t)(numTiles + 1) * 4 + 15) / 16) * 16;

    hipMemsetAsync(outd, 0, (size_t)3 * N * 4, stream);

    k_degrees<<<2048, 256, 0, stream>>>(src, dst, outd, ind, E);
    k_norms<<<(N + 255) / 256, 256, 0, stream>>>(outd, ind, nsrc, ndst, N);
    k_scan_partial<<<numTiles, 256, 0, stream>>>(ind, tilesum, N);
    k_scan_tiles<<<1, 64, 0, stream>>>(tilesum, rowptr, numTiles, N);
    k_scan_final<<<numTiles, 256, 0, stream>>>(ind, tilesum, rowptr, N);
    k_fill<<<2048, 256, 0, stream>>>(src, dst, rowptr, counter, colidx, E);

    int gblk = (N + 127) / 128;
    int ablk = 4096;
    k_gemm_norm<128><<<gblk, 256, 0, stream>>>(features, W0, nsrc, bufA, N);
    k_aggregate<128, true><<<ablk, 256, 0, stream>>>(bufA, rowptr, colidx, ndst, b0, bufB, N);
    k_gemm_norm<128><<<gblk, 256, 0, stream>>>(bufB, W1, nsrc, bufA, N);
    k_aggregate<128, true><<<ablk, 256, 0, stream>>>(bufA, rowptr, colidx, ndst, b1, bufB, N);
    k_gemm_norm<128><<<gblk, 256, 0, stream>>>(bufB, W2, nsrc, bufA, N);
    k_aggregate<128, true><<<ablk, 256, 0, stream>>>(bufA, rowptr, colidx, ndst, b2, bufB, N);
    k_gemm_norm<64><<<gblk, 256, 0, stream>>>(bufB, W3, nsrc, bufA, N);
    k_aggregate<64, false><<<ablk, 256, 0, stream>>>(bufA, rowptr, colidx, ndst, b3, out, N);
}

// Round 5
// 943.108 us; speedup vs baseline: 1.2873x; 1.0782x over previous
//
#include <hip/hip_runtime.h>
#include <cmath>

// ---------------- CSR build ----------------
// R3: 2E atomics total (the minimum: two histograms). Position-within-node is
// captured in pass1 (posw), so the fill pass needs NO atomics.

__global__ void k_pass1(const int* __restrict__ src, const int* __restrict__ dst,
                        int* __restrict__ outd, int* __restrict__ cnt,
                        int* __restrict__ posw, int E) {
    for (int i = blockIdx.x * blockDim.x + threadIdx.x; i < E; i += gridDim.x * blockDim.x) {
        atomicAdd(&outd[src[i]], 1);
        posw[i] = atomicAdd(&cnt[dst[i]], 1);
    }
}

__global__ void k_norms(const int* __restrict__ outd, const int* __restrict__ ind,
                        float* __restrict__ nsrc, float* __restrict__ ndst, int n) {
    int i = blockIdx.x * blockDim.x + threadIdx.x;
    if (i < n) {
        int od = outd[i], id = ind[i];
        nsrc[i] = od > 0 ? rsqrtf((float)od) : 0.f;
        ndst[i] = id > 0 ? rsqrtf((float)id) : 0.f;
    }
}

// ---------------- device-wide exclusive scan (tile = 2048) ----------------

constexpr int SCAN_TILE = 2048;

__global__ __launch_bounds__(256) void k_scan_partial(const int* __restrict__ deg,
                                                      int* __restrict__ tilesum, int n) {
    __shared__ int red[256];
    int base = blockIdx.x * SCAN_TILE;
    int s = 0;
    for (int i = threadIdx.x; i < SCAN_TILE; i += 256) {
        int idx = base + i;
        if (idx < n) s += deg[idx];
    }
    red[threadIdx.x] = s;
    __syncthreads();
    for (int off = 128; off > 0; off >>= 1) {
        if (threadIdx.x < off) red[threadIdx.x] += red[threadIdx.x + off];
        __syncthreads();
    }
    if (threadIdx.x == 0) tilesum[blockIdx.x] = red[0];
}

__global__ void k_scan_tiles(int* __restrict__ tilesum, int* __restrict__ rowptr,
                             int numTiles, int n) {
    if (threadIdx.x == 0 && blockIdx.x == 0) {
        int acc = 0;
        for (int i = 0; i < numTiles; i++) { int v = tilesum[i]; tilesum[i] = acc; acc += v; }
        rowptr[n] = acc;
    }
}

__global__ __launch_bounds__(256) void k_scan_final(const int* __restrict__ deg,
                                                    const int* __restrict__ tilesum,
                                                    int* __restrict__ rowptr, int n) {
    __shared__ int red[256];
    int base = blockIdx.x * SCAN_TILE;
    int lo = base + threadIdx.x * 8;
    int v[8]; int s = 0;
#pragma unroll
    for (int j = 0; j < 8; j++) {
        int idx = lo + j;
        v[j] = (idx < n) ? deg[idx] : 0;
        s += v[j];
    }
    red[threadIdx.x] = s;
    __syncthreads();
    for (int off = 1; off < 256; off <<= 1) {
        int x = red[threadIdx.x];
        int add = (threadIdx.x >= off) ? red[threadIdx.x - off] : 0;
        __syncthreads();
        red[threadIdx.x] = x + add;
        __syncthreads();
    }
    int excl = tilesum[blockIdx.x] + (threadIdx.x ? red[threadIdx.x - 1] : 0);
#pragma unroll
    for (int j = 0; j < 8; j++) {
        int idx = lo + j;
        if (idx < n) rowptr[idx] = excl;
        excl += v[j];
    }
}

// atomic-free fill: position was precomputed in pass1
__global__ void k_fill(const int* __restrict__ src, const int* __restrict__ dst,
                       const int* __restrict__ rowptr, const int* __restrict__ posw,
                       int* __restrict__ colidx, int E) {
    for (int i = blockIdx.x * blockDim.x + threadIdx.x; i < E; i += gridDim.x * blockDim.x) {
        int d = dst[i];
        colidx[rowptr[d] + posw[i]] = src[i];
    }
}

// ---------------- GEMM: h = (x @ W) * nsrc[:,None] ----------------

template <int DOUT>
__global__ __launch_bounds__(256) void k_gemm_norm(const float* __restrict__ x,
                                                   const float* __restrict__ W,
                                                   const float* __restrict__ nsrc,
                                                   float* __restrict__ h, int nrows) {
    constexpr int CPT = DOUT / 16;
    __shared__ float wt[DOUT * 128];

    {
        const float4* W4 = (const float4*)W;
        for (int idx = threadIdx.x; idx < 128 * (DOUT / 4); idx += 256) {
            int k = idx / (DOUT / 4);
            int c4 = (idx % (DOUT / 4)) * 4;
            float4 w = W4[idx];
            const float* wf = (const float*)&w;
#pragma unroll
            for (int j = 0; j < 4; j++) {
                int c = c4 + j;
                int swz = ((c >> 3) & 7) << 2;
                wt[c * 128 + (k ^ swz)] = wf[j];
            }
        }
    }
    __syncthreads();

    int rg = threadIdx.x >> 4;
    int cg = threadIdx.x & 15;
    int r0 = blockIdx.x * 128 + rg * 8;
    int c0 = cg * CPT;

    const float* xp[8];
#pragma unroll
    for (int r = 0; r < 8; r++) {
        int row = r0 + r;
        if (row >= nrows) row = nrows - 1;
        xp[r] = x + (size_t)row * 128;
    }

    float acc[8][CPT];
#pragma unroll
    for (int r = 0; r < 8; r++)
#pragma unroll
        for (int c = 0; c < CPT; c++) acc[r][c] = 0.f;

    for (int k = 0; k < 128; k += 4) {
        float4 wv[CPT];
#pragma unroll
        for (int c = 0; c < CPT; c++) {
            int cc = c0 + c;
            int swz = ((cc >> 3) & 7) << 2;
            wv[c] = *(const float4*)&wt[cc * 128 + (k ^ swz)];
        }
#pragma unroll
        for (int r = 0; r < 8; r++) {
            float4 xv = *(const float4*)(xp[r] + k);
#pragma unroll
            for (int c = 0; c < CPT; c++) {
                acc[r][c] += xv.x * wv[c].x;
                acc[r][c] += xv.y * wv[c].y;
                acc[r][c] += xv.z * wv[c].z;
                acc[r][c] += xv.w * wv[c].w;
            }
        }
    }

#pragma unroll
    for (int r = 0; r < 8; r++) {
        int row = r0 + r;
        if (row < nrows) {
            float nm = nsrc[row];
#pragma unroll
            for (int c = 0; c < CPT; c += 4) {
                float4 v = make_float4(acc[r][c] * nm, acc[r][c + 1] * nm,
                                       acc[r][c + 2] * nm, acc[r][c + 3] * nm);
                *(float4*)&h[(size_t)row * DOUT + c0 + c] = v;
            }
        }
    }
}

// ---------------- aggregation: wave-per-node ----------------
// R4 FIX: edge-batch loop trip count is now WAVE-UNIFORM (nb from wave-uniform
// m), so every lane is active in every iteration and every __shfl source lane
// is active. R3's per-group divergent loop made __shfl read lanes whose group
// had exited -> ds_bpermute from inactive lane = undefined -> wrong gathers on
// degree>=33 nodes (absmax 6.7e-3). All 4 slots now weight-guarded.

template <int D, bool ACT>
__global__ __launch_bounds__(256) void k_aggregate(const float* __restrict__ h,
                                                   const int* __restrict__ rowptr,
                                                   const int* __restrict__ colidx,
                                                   const float* __restrict__ ndst,
                                                   const float* __restrict__ bias,
                                                   float* __restrict__ out, int n) {
    constexpr int FB = D / 4;       // float4 blocks per row (32 or 16)
    constexpr int G  = 64 / FB;     // edge groups per wave (2 or 4)
    int wid  = (blockIdx.x * 256 + threadIdx.x) >> 6;
    int lane = threadIdx.x & 63;
    int fb = lane & (FB - 1);
    int g  = lane / FB;
    int waveCount = gridDim.x * 4;
    const float4* h4 = (const float4*)h;

    for (int node = wid; node < n; node += waveCount) {
        int beg = rowptr[node], end = rowptr[node + 1];
        float4 a0 = {0, 0, 0, 0}, a1 = {0, 0, 0, 0}, a2 = {0, 0, 0, 0}, a3 = {0, 0, 0, 0};

        for (int base = beg; base < end; base += 64) {
            int m = end - base; if (m > 64) m = 64;
            // one coalesced load covers up to 64 edges of this node
            int cv = colidx[base + (lane < m ? lane : 0)];
            int nb = (m + 4 * G - 1) / (4 * G);       // wave-uniform trip count
            for (int b = 0; b < nb; b++) {
                int j0 = g + b * 4 * G;
                int j1 = j0 + G, j2 = j0 + 2 * G, j3 = j0 + 3 * G;
                int q0 = j0 < m ? j0 : 0;
                int q1 = j1 < m ? j1 : 0;
                int q2 = j2 < m ? j2 : 0;
                int q3 = j3 < m ? j3 : 0;
                float w0 = j0 < m ? 1.f : 0.f;
                float w1 = j1 < m ? 1.f : 0.f;
                float w2 = j2 < m ? 1.f : 0.f;
                float w3 = j3 < m ? 1.f : 0.f;
                int s0 = __shfl(cv, q0);
                int s1 = __shfl(cv, q1);
                int s2 = __shfl(cv, q2);
                int s3 = __shfl(cv, q3);
                float4 v0 = h4[(size_t)s0 * FB + fb];
                float4 v1 = h4[(size_t)s1 * FB + fb];
                float4 v2 = h4[(size_t)s2 * FB + fb];
                float4 v3 = h4[(size_t)s3 * FB + fb];
                a0.x = fmaf(v0.x, w0, a0.x); a0.y = fmaf(v0.y, w0, a0.y);
                a0.z = fmaf(v0.z, w0, a0.z); a0.w = fmaf(v0.w, w0, a0.w);
                a1.x = fmaf(v1.x, w1, a1.x); a1.y = fmaf(v1.y, w1, a1.y);
                a1.z = fmaf(v1.z, w1, a1.z); a1.w = fmaf(v1.w, w1, a1.w);
                a2.x = fmaf(v2.x, w2, a2.x); a2.y = fmaf(v2.y, w2, a2.y);
                a2.z = fmaf(v2.z, w2, a2.z); a2.w = fmaf(v2.w, w2, a2.w);
                a3.x = fmaf(v3.x, w3, a3.x); a3.y = fmaf(v3.y, w3, a3.y);
                a3.z = fmaf(v3.z, w3, a3.z); a3.w = fmaf(v3.w, w3, a3.w);
            }
        }

        float4 acc;
        acc.x = (a0.x + a1.x) + (a2.x + a3.x);
        acc.y = (a0.y + a1.y) + (a2.y + a3.y);
        acc.z = (a0.z + a1.z) + (a2.z + a3.z);
        acc.w = (a0.w + a1.w) + (a2.w + a3.w);
#pragma unroll
        for (int off = FB; off < 64; off <<= 1) {
            acc.x += __shfl_xor(acc.x, off);
            acc.y += __shfl_xor(acc.y, off);
            acc.z += __shfl_xor(acc.z, off);
            acc.w += __shfl_xor(acc.w, off);
        }
        if (g == 0) {
            float nd = ndst[node];
            float4 bv = ((const float4*)bias)[fb];
            float4 v;
            v.x = acc.x * nd + bv.x;
            v.y = acc.y * nd + bv.y;
            v.z = acc.z * nd + bv.z;
            v.w = acc.w * nd + bv.w;
            if (ACT) {
                v.x = tanhf(v.x); v.y = tanhf(v.y);
                v.z = tanhf(v.z); v.w = tanhf(v.w);
            }
            ((float4*)out)[(size_t)node * FB + fb] = v;
        }
    }
}

// ---------------- host ----------------

extern "C" void kernel_launch(void* const* d_in, const int* in_sizes, int n_in,
                              void* d_out, int out_size, void* d_ws, size_t ws_size,
                              hipStream_t stream) {
    const float* features = (const float*)d_in[0];
    const int* edges      = (const int*)d_in[1];
    const float* W0 = (const float*)d_in[2]; const float* b0 = (const float*)d_in[3];
    const float* W1 = (const float*)d_in[4]; const float* b1 = (const float*)d_in[5];
    const float* W2 = (const float*)d_in[6]; const float* b2 = (const float*)d_in[7];
    const float* W3 = (const float*)d_in[8]; const float* b3 = (const float*)d_in[9];
    float* out = (float*)d_out;

    const int N = in_sizes[0] / 128;
    const int E = in_sizes[1] / 2;
    const int* src = edges;
    const int* dst = edges + E;
    const int numTiles = (N + SCAN_TILE - 1) / SCAN_TILE;

    char* p = (char*)d_ws;
    float* bufA   = (float*)p; p += (size_t)N * 128 * 4;
    float* bufB   = (float*)p; p += (size_t)N * 128 * 4;
    int*   rowptr = (int*)p;   p += (((size_t)(N + 1) * 4 + 15) / 16) * 16;
    int*   colidx = (int*)p;   p += (size_t)E * 4;
    int*   posw   = (int*)p;   p += (size_t)E * 4;
    int*   outd   = (int*)p;   p += (size_t)N * 4;
    int*   cnt    = (int*)p;   p += (size_t)N * 4;
    float* nsrc   = (float*)p; p += (size_t)N * 4;
    float* ndst   = (float*)p; p += (size_t)N * 4;
    int*   tilesum= (int*)p;   p += (((size_t)(numTiles + 1) * 4 + 15) / 16) * 16;

    hipMemsetAsync(outd, 0, (size_t)2 * N * 4, stream);   // outd, cnt contiguous

    k_pass1<<<2048, 256, 0, stream>>>(src, dst, outd, cnt, posw, E);
    k_norms<<<(N + 255) / 256, 256, 0, stream>>>(outd, cnt, nsrc, ndst, N);
    k_scan_partial<<<numTiles, 256, 0, stream>>>(cnt, tilesum, N);
    k_scan_tiles<<<1, 64, 0, stream>>>(tilesum, rowptr, numTiles, N);
    k_scan_final<<<numTiles, 256, 0, stream>>>(cnt, tilesum, rowptr, N);
    k_fill<<<2048, 256, 0, stream>>>(src, dst, rowptr, posw, colidx, E);

    int gblk = (N + 127) / 128;
    int ablk = 4096;
    k_gemm_norm<128><<<gblk, 256, 0, stream>>>(features, W0, nsrc, bufA, N);
    k_aggregate<128, true><<<ablk, 256, 0, stream>>>(bufA, rowptr, colidx, ndst, b0, bufB, N);
    k_gemm_norm<128><<<gblk, 256, 0, stream>>>(bufB, W1, nsrc, bufA, N);
    k_aggregate<128, true><<<ablk, 256, 0, stream>>>(bufA, rowptr, colidx, ndst, b1, bufB, N);
    k_gemm_norm<128><<<gblk, 256, 0, stream>>>(bufB, W2, nsrc, bufA, N);
    k_aggregate<128, true><<<ablk, 256, 0, stream>>>(bufA, rowptr, colidx, ndst, b2, bufB, N);
    k_gemm_norm<64><<<gblk, 256, 0, stream>>>(bufB, W3, nsrc, bufA, N);
    k_aggregate<64, false><<<ablk, 256, 0, stream>>>(bufA, rowptr, colidx, ndst, b3, out, N);
}

// Round 6
// 938.341 us; speedup vs baseline: 1.2939x; 1.0051x over previous
//
#include <hip/hip_runtime.h>
#include <cmath>

// ---------------- CSR build ----------------
// R3: 2E atomics total (the minimum: two histograms). Position-within-node is
// captured in pass1 (posw), so the fill pass needs NO atomics.

__global__ void k_pass1(const int* __restrict__ src, const int* __restrict__ dst,
                        int* __restrict__ outd, int* __restrict__ cnt,
                        int* __restrict__ posw, int E) {
    for (int i = blockIdx.x * blockDim.x + threadIdx.x; i < E; i += gridDim.x * blockDim.x) {
        atomicAdd(&outd[src[i]], 1);
        posw[i] = atomicAdd(&cnt[dst[i]], 1);
    }
}

__global__ void k_norms(const int* __restrict__ outd, const int* __restrict__ ind,
                        float* __restrict__ nsrc, float* __restrict__ ndst, int n) {
    int i = blockIdx.x * blockDim.x + threadIdx.x;
    if (i < n) {
        int od = outd[i], id = ind[i];
        nsrc[i] = od > 0 ? rsqrtf((float)od) : 0.f;
        ndst[i] = id > 0 ? rsqrtf((float)id) : 0.f;
    }
}

// ---------------- device-wide exclusive scan (tile = 2048) ----------------

constexpr int SCAN_TILE = 2048;

__global__ __launch_bounds__(256) void k_scan_partial(const int* __restrict__ deg,
                                                      int* __restrict__ tilesum, int n) {
    __shared__ int red[256];
    int base = blockIdx.x * SCAN_TILE;
    int s = 0;
    for (int i = threadIdx.x; i < SCAN_TILE; i += 256) {
        int idx = base + i;
        if (idx < n) s += deg[idx];
    }
    red[threadIdx.x] = s;
    __syncthreads();
    for (int off = 128; off > 0; off >>= 1) {
        if (threadIdx.x < off) red[threadIdx.x] += red[threadIdx.x + off];
        __syncthreads();
    }
    if (threadIdx.x == 0) tilesum[blockIdx.x] = red[0];
}

__global__ void k_scan_tiles(int* __restrict__ tilesum, int* __restrict__ rowptr,
                             int numTiles, int n) {
    if (threadIdx.x == 0 && blockIdx.x == 0) {
        int acc = 0;
        for (int i = 0; i < numTiles; i++) { int v = tilesum[i]; tilesum[i] = acc; acc += v; }
        rowptr[n] = acc;
    }
}

__global__ __launch_bounds__(256) void k_scan_final(const int* __restrict__ deg,
                                                    const int* __restrict__ tilesum,
                                                    int* __restrict__ rowptr, int n) {
    __shared__ int red[256];
    int base = blockIdx.x * SCAN_TILE;
    int lo = base + threadIdx.x * 8;
    int v[8]; int s = 0;
#pragma unroll
    for (int j = 0; j < 8; j++) {
        int idx = lo + j;
        v[j] = (idx < n) ? deg[idx] : 0;
        s += v[j];
    }
    red[threadIdx.x] = s;
    __syncthreads();
    for (int off = 1; off < 256; off <<= 1) {
        int x = red[threadIdx.x];
        int add = (threadIdx.x >= off) ? red[threadIdx.x - off] : 0;
        __syncthreads();
        red[threadIdx.x] = x + add;
        __syncthreads();
    }
    int excl = tilesum[blockIdx.x] + (threadIdx.x ? red[threadIdx.x - 1] : 0);
#pragma unroll
    for (int j = 0; j < 8; j++) {
        int idx = lo + j;
        if (idx < n) rowptr[idx] = excl;
        excl += v[j];
    }
}

// atomic-free fill: position was precomputed in pass1
__global__ void k_fill(const int* __restrict__ src, const int* __restrict__ dst,
                       const int* __restrict__ rowptr, const int* __restrict__ posw,
                       int* __restrict__ colidx, int E) {
    for (int i = blockIdx.x * blockDim.x + threadIdx.x; i < E; i += gridDim.x * blockDim.x) {
        int d = dst[i];
        colidx[rowptr[d] + posw[i]] = src[i];
    }
}

// ---------------- GEMM: h = (x @ W) * nsrc[:,None] ----------------

template <int DOUT>
__global__ __launch_bounds__(256) void k_gemm_norm(const float* __restrict__ x,
                                                   const float* __restrict__ W,
                                                   const float* __restrict__ nsrc,
                                                   float* __restrict__ h, int nrows) {
    constexpr int CPT = DOUT / 16;
    __shared__ float wt[DOUT * 128];

    {
        const float4* W4 = (const float4*)W;
        for (int idx = threadIdx.x; idx < 128 * (DOUT / 4); idx += 256) {
            int k = idx / (DOUT / 4);
            int c4 = (idx % (DOUT / 4)) * 4;
            float4 w = W4[idx];
            const float* wf = (const float*)&w;
#pragma unroll
            for (int j = 0; j < 4; j++) {
                int c = c4 + j;
                int swz = ((c >> 3) & 7) << 2;
                wt[c * 128 + (k ^ swz)] = wf[j];
            }
        }
    }
    __syncthreads();

    int rg = threadIdx.x >> 4;
    int cg = threadIdx.x & 15;
    int r0 = blockIdx.x * 128 + rg * 8;
    int c0 = cg * CPT;

    const float* xp[8];
#pragma unroll
    for (int r = 0; r < 8; r++) {
        int row = r0 + r;
        if (row >= nrows) row = nrows - 1;
        xp[r] = x + (size_t)row * 128;
    }

    float acc[8][CPT];
#pragma unroll
    for (int r = 0; r < 8; r++)
#pragma unroll
        for (int c = 0; c < CPT; c++) acc[r][c] = 0.f;

    for (int k = 0; k < 128; k += 4) {
        float4 wv[CPT];
#pragma unroll
        for (int c = 0; c < CPT; c++) {
            int cc = c0 + c;
            int swz = ((cc >> 3) & 7) << 2;
            wv[c] = *(const float4*)&wt[cc * 128 + (k ^ swz)];
        }
#pragma unroll
        for (int r = 0; r < 8; r++) {
            float4 xv = *(const float4*)(xp[r] + k);
#pragma unroll
            for (int c = 0; c < CPT; c++) {
                acc[r][c] += xv.x * wv[c].x;
                acc[r][c] += xv.y * wv[c].y;
                acc[r][c] += xv.z * wv[c].z;
                acc[r][c] += xv.w * wv[c].w;
            }
        }
    }

#pragma unroll
    for (int r = 0; r < 8; r++) {
        int row = r0 + r;
        if (row < nrows) {
            float nm = nsrc[row];
#pragma unroll
            for (int c = 0; c < CPT; c += 4) {
                float4 v = make_float4(acc[r][c] * nm, acc[r][c + 1] * nm,
                                       acc[r][c + 2] * nm, acc[r][c + 3] * nm);
                *(float4*)&h[(size_t)row * DOUT + c0 + c] = v;
            }
        }
    }
}

// ---------------- aggregation: wave-per-node, MLP=8 ----------------
// R5: aggregates are latency-bound (R2 PMC: VALUBusy 19%, hbm 39%, occ 70%;
// h fits L3 but misses 4MB per-XCD L2 -> ~350-900cy gathers). 8 independent
// row-gathers in flight per group (one batch covers a deg-16 node at G=2).
// Invariant from R4: batch trip count is wave-uniform so every __shfl source
// lane is active; all slots weight-guarded.

template <int D, bool ACT>
__global__ __launch_bounds__(256) void k_aggregate(const float* __restrict__ h,
                                                   const int* __restrict__ rowptr,
                                                   const int* __restrict__ colidx,
                                                   const float* __restrict__ ndst,
                                                   const float* __restrict__ bias,
                                                   float* __restrict__ out, int n) {
    constexpr int FB = D / 4;       // float4 blocks per row (32 or 16)
    constexpr int G  = 64 / FB;     // edge groups per wave (2 or 4)
    constexpr int U  = 8;           // gathers in flight per group
    constexpr int UG = U * G;       // edges per batch
    int wid  = (blockIdx.x * 256 + threadIdx.x) >> 6;
    int lane = threadIdx.x & 63;
    int fb = lane & (FB - 1);
    int g  = lane / FB;
    int waveCount = gridDim.x * 4;
    const float4* h4 = (const float4*)h;

    for (int node = wid; node < n; node += waveCount) {
        int beg = rowptr[node], end = rowptr[node + 1];
        float4 a0 = {0, 0, 0, 0}, a1 = {0, 0, 0, 0}, a2 = {0, 0, 0, 0}, a3 = {0, 0, 0, 0};

        for (int base = beg; base < end; base += 64) {
            int m = end - base; if (m > 64) m = 64;
            // one coalesced load covers up to 64 edges of this node
            int cv = colidx[base + (lane < m ? lane : 0)];
            int nb = (m + UG - 1) / UG;       // wave-uniform trip count
            for (int b = 0; b < nb; b++) {
                int s[U]; float w[U];
#pragma unroll
                for (int u = 0; u < U; u++) {
                    int j = b * UG + u * G + g;
                    int q = j < m ? j : 0;
                    w[u] = j < m ? 1.f : 0.f;
                    s[u] = __shfl(cv, q);
                }
                float4 v[U];
#pragma unroll
                for (int u = 0; u < U; u++)
                    v[u] = h4[(size_t)s[u] * FB + fb];
#pragma unroll
                for (int u = 0; u < U; u += 4) {
                    a0.x = fmaf(v[u].x, w[u], a0.x); a0.y = fmaf(v[u].y, w[u], a0.y);
                    a0.z = fmaf(v[u].z, w[u], a0.z); a0.w = fmaf(v[u].w, w[u], a0.w);
                    a1.x = fmaf(v[u+1].x, w[u+1], a1.x); a1.y = fmaf(v[u+1].y, w[u+1], a1.y);
                    a1.z = fmaf(v[u+1].z, w[u+1], a1.z); a1.w = fmaf(v[u+1].w, w[u+1], a1.w);
                    a2.x = fmaf(v[u+2].x, w[u+2], a2.x); a2.y = fmaf(v[u+2].y, w[u+2], a2.y);
                    a2.z = fmaf(v[u+2].z, w[u+2], a2.z); a2.w = fmaf(v[u+2].w, w[u+2], a2.w);
                    a3.x = fmaf(v[u+3].x, w[u+3], a3.x); a3.y = fmaf(v[u+3].y, w[u+3], a3.y);
                    a3.z = fmaf(v[u+3].z, w[u+3], a3.z); a3.w = fmaf(v[u+3].w, w[u+3], a3.w);
                }
            }
        }

        float4 acc;
        acc.x = (a0.x + a1.x) + (a2.x + a3.x);
        acc.y = (a0.y + a1.y) + (a2.y + a3.y);
        acc.z = (a0.z + a1.z) + (a2.z + a3.z);
        acc.w = (a0.w + a1.w) + (a2.w + a3.w);
#pragma unroll
        for (int off = FB; off < 64; off <<= 1) {
            acc.x += __shfl_xor(acc.x, off);
            acc.y += __shfl_xor(acc.y, off);
            acc.z += __shfl_xor(acc.z, off);
            acc.w += __shfl_xor(acc.w, off);
        }
        if (g == 0) {
            float nd = ndst[node];
            float4 bv = ((const float4*)bias)[fb];
            float4 v;
            v.x = acc.x * nd + bv.x;
            v.y = acc.y * nd + bv.y;
            v.z = acc.z * nd + bv.z;
            v.w = acc.w * nd + bv.w;
            if (ACT) {
                v.x = tanhf(v.x); v.y = tanhf(v.y);
                v.z = tanhf(v.z); v.w = tanhf(v.w);
            }
            ((float4*)out)[(size_t)node * FB + fb] = v;
        }
    }
}

// ---------------- host ----------------

extern "C" void kernel_launch(void* const* d_in, const int* in_sizes, int n_in,
                              void* d_out, int out_size, void* d_ws, size_t ws_size,
                              hipStream_t stream) {
    const float* features = (const float*)d_in[0];
    const int* edges      = (const int*)d_in[1];
    const float* W0 = (const float*)d_in[2]; const float* b0 = (const float*)d_in[3];
    const float* W1 = (const float*)d_in[4]; const float* b1 = (const float*)d_in[5];
    const float* W2 = (const float*)d_in[6]; const float* b2 = (const float*)d_in[7];
    const float* W3 = (const float*)d_in[8]; const float* b3 = (const float*)d_in[9];
    float* out = (float*)d_out;

    const int N = in_sizes[0] / 128;
    const int E = in_sizes[1] / 2;
    const int* src = edges;
    const int* dst = edges + E;
    const int numTiles = (N + SCAN_TILE - 1) / SCAN_TILE;

    char* p = (char*)d_ws;
    float* bufA   = (float*)p; p += (size_t)N * 128 * 4;
    float* bufB   = (float*)p; p += (size_t)N * 128 * 4;
    int*   rowptr = (int*)p;   p += (((size_t)(N + 1) * 4 + 15) / 16) * 16;
    int*   colidx = (int*)p;   p += (size_t)E * 4;
    int*   posw   = (int*)p;   p += (size_t)E * 4;
    int*   outd   = (int*)p;   p += (size_t)N * 4;
    int*   cnt    = (int*)p;   p += (size_t)N * 4;
    float* nsrc   = (float*)p; p += (size_t)N * 4;
    float* ndst   = (float*)p; p += (size_t)N * 4;
    int*   tilesum= (int*)p;   p += (((size_t)(numTiles + 1) * 4 + 15) / 16) * 16;

    hipMemsetAsync(outd, 0, (size_t)2 * N * 4, stream);   // outd, cnt contiguous

    k_pass1<<<2048, 256, 0, stream>>>(src, dst, outd, cnt, posw, E);
    k_norms<<<(N + 255) / 256, 256, 0, stream>>>(outd, cnt, nsrc, ndst, N);
    k_scan_partial<<<numTiles, 256, 0, stream>>>(cnt, tilesum, N);
    k_scan_tiles<<<1, 64, 0, stream>>>(tilesum, rowptr, numTiles, N);
    k_scan_final<<<numTiles, 256, 0, stream>>>(cnt, tilesum, rowptr, N);
    k_fill<<<2048, 256, 0, stream>>>(src, dst, rowptr, posw, colidx, E);

    int gblk = (N + 127) / 128;
    int ablk = 4096;
    k_gemm_norm<128><<<gblk, 256, 0, stream>>>(features, W0, nsrc, bufA, N);
    k_aggregate<128, true><<<ablk, 256, 0, stream>>>(bufA, rowptr, colidx, ndst, b0, bufB, N);
    k_gemm_norm<128><<<gblk, 256, 0, stream>>>(bufB, W1, nsrc, bufA, N);
    k_aggregate<128, true><<<ablk, 256, 0, stream>>>(bufA, rowptr, colidx, ndst, b1, bufB, N);
    k_gemm_norm<128><<<gblk, 256, 0, stream>>>(bufB, W2, nsrc, bufA, N);
    k_aggregate<128, true><<<ablk, 256, 0, stream>>>(bufA, rowptr, colidx, ndst, b2, bufB, N);
    k_gemm_norm<64><<<gblk, 256, 0, stream>>>(bufB, W3, nsrc, bufA, N);
    k_aggregate<64, false><<<ablk, 256, 0, stream>>>(bufA, rowptr, colidx, ndst, b3, out, N);
}

// Round 7
// 830.463 us; speedup vs baseline: 1.4620x; 1.1299x over previous
//
#include <hip/hip_runtime.h>
#include <cmath>

typedef __attribute__((ext_vector_type(8))) short bf16x8;
typedef __attribute__((ext_vector_type(4))) float f32x4;

__device__ inline unsigned short f2bf_rne(float f) {
    unsigned int u = __float_as_uint(f);
    unsigned int r = (u + 0x7FFFu + ((u >> 16) & 1u)) >> 16;
    return (unsigned short)r;
}
__device__ inline float bf2f(unsigned short h) {
    return __uint_as_float(((unsigned int)h) << 16);
}

// ---------------- CSR build ----------------

__global__ void k_pass1(const int* __restrict__ src, const int* __restrict__ dst,
                        int* __restrict__ outd, int* __restrict__ cnt,
                        int* __restrict__ posw, int E) {
    for (int i = blockIdx.x * blockDim.x + threadIdx.x; i < E; i += gridDim.x * blockDim.x) {
        atomicAdd(&outd[src[i]], 1);
        posw[i] = atomicAdd(&cnt[dst[i]], 1);
    }
}

__global__ void k_norms(const int* __restrict__ outd, const int* __restrict__ ind,
                        float* __restrict__ nsrc, float* __restrict__ ndst, int n) {
    int i = blockIdx.x * blockDim.x + threadIdx.x;
    if (i < n) {
        int od = outd[i], id = ind[i];
        nsrc[i] = od > 0 ? rsqrtf((float)od) : 0.f;
        ndst[i] = id > 0 ? rsqrtf((float)id) : 0.f;
    }
}

// W (fp32, k-major [k][n]) -> Wt hi/lo (bf16, n-major [n][k]), all 4 layers in one launch
__global__ void k_prepW_all(const float* __restrict__ W0, const float* __restrict__ W1,
                            const float* __restrict__ W2, const float* __restrict__ W3,
                            unsigned short* __restrict__ h0, unsigned short* __restrict__ l0,
                            unsigned short* __restrict__ h1, unsigned short* __restrict__ l1,
                            unsigned short* __restrict__ h2, unsigned short* __restrict__ l2,
                            unsigned short* __restrict__ h3, unsigned short* __restrict__ l3) {
    int i = blockIdx.x * 256 + threadIdx.x;
    const float* W; unsigned short* wh; unsigned short* wl; int N; int base;
    if      (i < 16384) { W = W0; wh = h0; wl = l0; N = 128; base = i; }
    else if (i < 32768) { W = W1; wh = h1; wl = l1; N = 128; base = i - 16384; }
    else if (i < 49152) { W = W2; wh = h2; wl = l2; N = 128; base = i - 32768; }
    else if (i < 57344) { W = W3; wh = h3; wl = l3; N = 64;  base = i - 49152; }
    else return;
    int n = base >> 7, k = base & 127;
    float w = W[k * N + n];
    unsigned short hb = f2bf_rne(w);
    unsigned short lb = f2bf_rne(w - bf2f(hb));
    wh[base] = hb; wl[base] = lb;
}

// ---------------- device-wide exclusive scan (tile = 2048) ----------------

constexpr int SCAN_TILE = 2048;

__global__ __launch_bounds__(256) void k_scan_partial(const int* __restrict__ deg,
                                                      int* __restrict__ tilesum, int n) {
    __shared__ int red[256];
    int base = blockIdx.x * SCAN_TILE;
    int s = 0;
    for (int i = threadIdx.x; i < SCAN_TILE; i += 256) {
        int idx = base + i;
        if (idx < n) s += deg[idx];
    }
    red[threadIdx.x] = s;
    __syncthreads();
    for (int off = 128; off > 0; off >>= 1) {
        if (threadIdx.x < off) red[threadIdx.x] += red[threadIdx.x + off];
        __syncthreads();
    }
    if (threadIdx.x == 0) tilesum[blockIdx.x] = red[0];
}

__global__ void k_scan_tiles(int* __restrict__ tilesum, int* __restrict__ rowptr,
                             int numTiles, int n) {
    if (threadIdx.x == 0 && blockIdx.x == 0) {
        int acc = 0;
        for (int i = 0; i < numTiles; i++) { int v = tilesum[i]; tilesum[i] = acc; acc += v; }
        rowptr[n] = acc;
    }
}

__global__ __launch_bounds__(256) void k_scan_final(const int* __restrict__ deg,
                                                    const int* __restrict__ tilesum,
                                                    int* __restrict__ rowptr, int n) {
    __shared__ int red[256];
    int base = blockIdx.x * SCAN_TILE;
    int lo = base + threadIdx.x * 8;
    int v[8]; int s = 0;
#pragma unroll
    for (int j = 0; j < 8; j++) {
        int idx = lo + j;
        v[j] = (idx < n) ? deg[idx] : 0;
        s += v[j];
    }
    red[threadIdx.x] = s;
    __syncthreads();
    for (int off = 1; off < 256; off <<= 1) {
        int x = red[threadIdx.x];
        int add = (threadIdx.x >= off) ? red[threadIdx.x - off] : 0;
        __syncthreads();
        red[threadIdx.x] = x + add;
        __syncthreads();
    }
    int excl = tilesum[blockIdx.x] + (threadIdx.x ? red[threadIdx.x - 1] : 0);
#pragma unroll
    for (int j = 0; j < 8; j++) {
        int idx = lo + j;
        if (idx < n) rowptr[idx] = excl;
        excl += v[j];
    }
}

__global__ void k_fill(const int* __restrict__ src, const int* __restrict__ dst,
                       const int* __restrict__ rowptr, const int* __restrict__ posw,
                       int* __restrict__ colidx, int E) {
    for (int i = blockIdx.x * blockDim.x + threadIdx.x; i < E; i += gridDim.x * blockDim.x) {
        int d = dst[i];
        colidx[rowptr[d] + posw[i]] = src[i];
    }
}

// ---------------- GEMM via split-bf16 MFMA: h = (x @ W) * nsrc[:,None] ----------------
// R6: x = hi+lo bf16, W = Hi+Lo bf16 (pre-transposed). C = hi@Hi + hi@Lo + lo@Hi
// in fp32 AGPRs (dropped lo@Lo term ~4e-6 abs). 64-row blocks, K staged in two
// halves (55 KB LDS -> 2 blocks/CU). Layouts (m89/m120-verified):
// A[m=lane&15][k=quad*8+j], B[k=quad*8+j][n=lane&15], C row=quad*4+reg, col=lane&15.
// Row stride 72 ushorts = 144 B -> 16B-aligned b128, <=2-way bank conflict (free).

template <int DOUT, int SRC>   // SRC 0: fp32 x input (convert in staging); 1: bf16 hi/lo
__global__ __launch_bounds__(256) void k_gemm_mfma(
        const float* __restrict__ xf,
        const unsigned short* __restrict__ xhi, const unsigned short* __restrict__ xlo,
        const unsigned short* __restrict__ wth, const unsigned short* __restrict__ wtl,
        const float* __restrict__ nsrc, float* __restrict__ h, int nrows) {
    constexpr int NP = DOUT / 64;    // n-tiles per wave (2 for DOUT=128, 1 for 64)
    constexpr int LDK = 72;          // 64 + 8 pad (keeps 16B row alignment)
    __shared__ unsigned short Ah[64 * LDK], Al[64 * LDK];
    __shared__ unsigned short Bh[DOUT * LDK], Bl[DOUT * LDK];
    __shared__ float ns[64];

    int tid = threadIdx.x;
    int row0 = blockIdx.x * 64;
    int lane = tid & 63;
    int wv = tid >> 6;
    int quad = lane >> 4, l16 = lane & 15;

    if (tid < 64) {
        int row = row0 + tid; if (row >= nrows) row = nrows - 1;
        ns[tid] = nsrc[row];
    }

    f32x4 acc[4][NP];
#pragma unroll
    for (int mp = 0; mp < 4; mp++)
#pragma unroll
        for (int npi = 0; npi < NP; npi++)
            acc[mp][npi] = (f32x4){0.f, 0.f, 0.f, 0.f};

    for (int kh = 0; kh < 2; kh++) {
        if (kh) __syncthreads();
        // stage A (64 rows x 64 k of this half)
        for (int i = tid; i < 64 * 16; i += 256) {
            int r = i >> 4, kb = i & 15;
            int row = row0 + r; if (row >= nrows) row = nrows - 1;
            int koff = kh * 64 + kb * 4;
            if (SRC == 0) {
                float4 xv = *(const float4*)&xf[(size_t)row * 128 + koff];
                ushort4 hv, lv;
                hv.x = f2bf_rne(xv.x); lv.x = f2bf_rne(xv.x - bf2f(hv.x));
                hv.y = f2bf_rne(xv.y); lv.y = f2bf_rne(xv.y - bf2f(hv.y));
                hv.z = f2bf_rne(xv.z); lv.z = f2bf_rne(xv.z - bf2f(hv.z));
                hv.w = f2bf_rne(xv.w); lv.w = f2bf_rne(xv.w - bf2f(hv.w));
                *(ushort4*)&Ah[r * LDK + kb * 4] = hv;
                *(ushort4*)&Al[r * LDK + kb * 4] = lv;
            } else {
                *(ushort4*)&Ah[r * LDK + kb * 4] = *(const ushort4*)&xhi[(size_t)row * 128 + koff];
                *(ushort4*)&Al[r * LDK + kb * 4] = *(const ushort4*)&xlo[(size_t)row * 128 + koff];
            }
        }
        // stage B (DOUT n-rows x 64 k of this half)
        for (int i = tid; i < DOUT * 16; i += 256) {
            int n = i >> 4, kb = i & 15;
            int koff = kh * 64 + kb * 4;
            *(ushort4*)&Bh[n * LDK + kb * 4] = *(const ushort4*)&wth[n * 128 + koff];
            *(ushort4*)&Bl[n * LDK + kb * 4] = *(const ushort4*)&wtl[n * 128 + koff];
        }
        __syncthreads();

        for (int kq = 0; kq < 2; kq++) {
            int ko = kq * 32 + quad * 8;
            bf16x8 ah[4], al[4], bh[NP], bl[NP];
#pragma unroll
            for (int mp = 0; mp < 4; mp++) {
                ah[mp] = *(const bf16x8*)&Ah[(mp * 16 + l16) * LDK + ko];
                al[mp] = *(const bf16x8*)&Al[(mp * 16 + l16) * LDK + ko];
            }
#pragma unroll
            for (int npi = 0; npi < NP; npi++) {
                int n = (wv * NP + npi) * 16 + l16;
                bh[npi] = *(const bf16x8*)&Bh[n * LDK + ko];
                bl[npi] = *(const bf16x8*)&Bl[n * LDK + ko];
            }
#pragma unroll
            for (int mp = 0; mp < 4; mp++)
#pragma unroll
                for (int npi = 0; npi < NP; npi++) {
                    acc[mp][npi] = __builtin_amdgcn_mfma_f32_16x16x32_bf16(ah[mp], bh[npi], acc[mp][npi], 0, 0, 0);
                    acc[mp][npi] = __builtin_amdgcn_mfma_f32_16x16x32_bf16(ah[mp], bl[npi], acc[mp][npi], 0, 0, 0);
                    acc[mp][npi] = __builtin_amdgcn_mfma_f32_16x16x32_bf16(al[mp], bh[npi], acc[mp][npi], 0, 0, 0);
                }
        }
    }

#pragma unroll
    for (int mp = 0; mp < 4; mp++) {
#pragma unroll
        for (int r = 0; r < 4; r++) {
            int rl = mp * 16 + quad * 4 + r;
            int row = row0 + rl;
            if (row < nrows) {
                float nm = ns[rl];
#pragma unroll
                for (int npi = 0; npi < NP; npi++) {
                    int col = (wv * NP + npi) * 16 + l16;
                    h[(size_t)row * DOUT + col] = acc[mp][npi][r] * nm;
                }
            }
        }
    }
}

// ---------------- aggregation: wave-per-node, MLP=8 ----------------
// MODE 1: tanh + write bf16 hi/lo pair (same bytes as fp32) for next MFMA GEMM.
// MODE 0: no act + fp32 out (final layer).
// Invariant (R4): batch trip count wave-uniform so every __shfl source lane is
// active; all slots weight-guarded.

template <int D, int MODE>
__global__ __launch_bounds__(256) void k_aggregate(const float* __restrict__ h,
                                                   const int* __restrict__ rowptr,
                                                   const int* __restrict__ colidx,
                                                   const float* __restrict__ ndst,
                                                   const float* __restrict__ bias,
                                                   float* __restrict__ out,
                                                   unsigned short* __restrict__ ohi,
                                                   unsigned short* __restrict__ olo,
                                                   int n) {
    constexpr int FB = D / 4;       // float4 blocks per row (32 or 16)
    constexpr int G  = 64 / FB;     // edge groups per wave (2 or 4)
    constexpr int U  = 8;           // gathers in flight per group
    constexpr int UG = U * G;
    int wid  = (blockIdx.x * 256 + threadIdx.x) >> 6;
    int lane = threadIdx.x & 63;
    int fb = lane & (FB - 1);
    int g  = lane / FB;
    int waveCount = gridDim.x * 4;
    const float4* h4 = (const float4*)h;

    for (int node = wid; node < n; node += waveCount) {
        int beg = rowptr[node], end = rowptr[node + 1];
        float4 a0 = {0, 0, 0, 0}, a1 = {0, 0, 0, 0}, a2 = {0, 0, 0, 0}, a3 = {0, 0, 0, 0};

        for (int base = beg; base < end; base += 64) {
            int m = end - base; if (m > 64) m = 64;
            int cv = colidx[base + (lane < m ? lane : 0)];
            int nb = (m + UG - 1) / UG;       // wave-uniform trip count
            for (int b = 0; b < nb; b++) {
                int s[U]; float w[U];
#pragma unroll
                for (int u = 0; u < U; u++) {
                    int j = b * UG + u * G + g;
                    int q = j < m ? j : 0;
                    w[u] = j < m ? 1.f : 0.f;
                    s[u] = __shfl(cv, q);
                }
                float4 v[U];
#pragma unroll
                for (int u = 0; u < U; u++)
                    v[u] = h4[(size_t)s[u] * FB + fb];
#pragma unroll
                for (int u = 0; u < U; u += 4) {
                    a0.x = fmaf(v[u].x, w[u], a0.x); a0.y = fmaf(v[u].y, w[u], a0.y);
                    a0.z = fmaf(v[u].z, w[u], a0.z); a0.w = fmaf(v[u].w, w[u], a0.w);
                    a1.x = fmaf(v[u+1].x, w[u+1], a1.x); a1.y = fmaf(v[u+1].y, w[u+1], a1.y);
                    a1.z = fmaf(v[u+1].z, w[u+1], a1.z); a1.w = fmaf(v[u+1].w, w[u+1], a1.w);
                    a2.x = fmaf(v[u+2].x, w[u+2], a2.x); a2.y = fmaf(v[u+2].y, w[u+2], a2.y);
                    a2.z = fmaf(v[u+2].z, w[u+2], a2.z); a2.w = fmaf(v[u+2].w, w[u+2], a2.w);
                    a3.x = fmaf(v[u+3].x, w[u+3], a3.x); a3.y = fmaf(v[u+3].y, w[u+3], a3.y);
                    a3.z = fmaf(v[u+3].z, w[u+3], a3.z); a3.w = fmaf(v[u+3].w, w[u+3], a3.w);
                }
            }
        }

        float4 acc;
        acc.x = (a0.x + a1.x) + (a2.x + a3.x);
        acc.y = (a0.y + a1.y) + (a2.y + a3.y);
        acc.z = (a0.z + a1.z) + (a2.z + a3.z);
        acc.w = (a0.w + a1.w) + (a2.w + a3.w);
#pragma unroll
        for (int off = FB; off < 64; off <<= 1) {
            acc.x += __shfl_xor(acc.x, off);
            acc.y += __shfl_xor(acc.y, off);
            acc.z += __shfl_xor(acc.z, off);
            acc.w += __shfl_xor(acc.w, off);
        }
        if (g == 0) {
            float nd = ndst[node];
            float4 bv = ((const float4*)bias)[fb];
            float4 v;
            v.x = acc.x * nd + bv.x;
            v.y = acc.y * nd + bv.y;
            v.z = acc.z * nd + bv.z;
            v.w = acc.w * nd + bv.w;
            if (MODE == 1) {
                v.x = tanhf(v.x); v.y = tanhf(v.y);
                v.z = tanhf(v.z); v.w = tanhf(v.w);
                ushort4 hv, lv;
                hv.x = f2bf_rne(v.x); lv.x = f2bf_rne(v.x - bf2f(hv.x));
                hv.y = f2bf_rne(v.y); lv.y = f2bf_rne(v.y - bf2f(hv.y));
                hv.z = f2bf_rne(v.z); lv.z = f2bf_rne(v.z - bf2f(hv.z));
                hv.w = f2bf_rne(v.w); lv.w = f2bf_rne(v.w - bf2f(hv.w));
                *(ushort4*)&ohi[(size_t)node * D + fb * 4] = hv;
                *(ushort4*)&olo[(size_t)node * D + fb * 4] = lv;
            } else {
                ((float4*)out)[(size_t)node * FB + fb] = v;
            }
        }
    }
}

// ---------------- host ----------------

extern "C" void kernel_launch(void* const* d_in, const int* in_sizes, int n_in,
                              void* d_out, int out_size, void* d_ws, size_t ws_size,
                              hipStream_t stream) {
    const float* features = (const float*)d_in[0];
    const int* edges      = (const int*)d_in[1];
    const float* W0 = (const float*)d_in[2]; const float* b0 = (const float*)d_in[3];
    const float* W1 = (const float*)d_in[4]; const float* b1 = (const float*)d_in[5];
    const float* W2 = (const float*)d_in[6]; const float* b2 = (const float*)d_in[7];
    const float* W3 = (const float*)d_in[8]; const float* b3 = (const float*)d_in[9];
    float* out = (float*)d_out;

    const int N = in_sizes[0] / 128;
    const int E = in_sizes[1] / 2;
    const int* src = edges;
    const int* dst = edges + E;
    const int numTiles = (N + SCAN_TILE - 1) / SCAN_TILE;

    char* p = (char*)d_ws;
    float* bufH            = (float*)p;          p += (size_t)N * 128 * 4;
    unsigned short* xhi    = (unsigned short*)p; p += (size_t)N * 128 * 2;
    unsigned short* xlo    = (unsigned short*)p; p += (size_t)N * 128 * 2;
    int*   rowptr = (int*)p;   p += (((size_t)(N + 1) * 4 + 15) / 16) * 16;
    int*   colidx = (int*)p;   p += (size_t)E * 4;
    int*   posw   = (int*)p;   p += (size_t)E * 4;
    int*   outd   = (int*)p;   p += (size_t)N * 4;
    int*   cnt    = (int*)p;   p += (size_t)N * 4;
    float* nsrc   = (float*)p; p += (size_t)N * 4;
    float* ndst   = (float*)p; p += (size_t)N * 4;
    int*   tilesum= (int*)p;   p += (((size_t)(numTiles + 1) * 4 + 15) / 16) * 16;
    unsigned short* wt0h = (unsigned short*)p; p += 16384 * 2;
    unsigned short* wt0l = (unsigned short*)p; p += 16384 * 2;
    unsigned short* wt1h = (unsigned short*)p; p += 16384 * 2;
    unsigned short* wt1l = (unsigned short*)p; p += 16384 * 2;
    unsigned short* wt2h = (unsigned short*)p; p += 16384 * 2;
    unsigned short* wt2l = (unsigned short*)p; p += 16384 * 2;
    unsigned short* wt3h = (unsigned short*)p; p += 8192 * 2;
    unsigned short* wt3l = (unsigned short*)p; p += 8192 * 2;

    hipMemsetAsync(outd, 0, (size_t)2 * N * 4, stream);   // outd, cnt contiguous

    k_prepW_all<<<224, 256, 0, stream>>>(W0, W1, W2, W3, wt0h, wt0l, wt1h, wt1l,
                                         wt2h, wt2l, wt3h, wt3l);
    k_pass1<<<2048, 256, 0, stream>>>(src, dst, outd, cnt, posw, E);
    k_norms<<<(N + 255) / 256, 256, 0, stream>>>(outd, cnt, nsrc, ndst, N);
    k_scan_partial<<<numTiles, 256, 0, stream>>>(cnt, tilesum, N);
    k_scan_tiles<<<1, 64, 0, stream>>>(tilesum, rowptr, numTiles, N);
    k_scan_final<<<numTiles, 256, 0, stream>>>(cnt, tilesum, rowptr, N);
    k_fill<<<2048, 256, 0, stream>>>(src, dst, rowptr, posw, colidx, E);

    int gblk = (N + 63) / 64;
    int ablk = 4096;
    k_gemm_mfma<128, 0><<<gblk, 256, 0, stream>>>(features, nullptr, nullptr, wt0h, wt0l, nsrc, bufH, N);
    k_aggregate<128, 1><<<ablk, 256, 0, stream>>>(bufH, rowptr, colidx, ndst, b0, nullptr, xhi, xlo, N);
    k_gemm_mfma<128, 1><<<gblk, 256, 0, stream>>>(nullptr, xhi, xlo, wt1h, wt1l, nsrc, bufH, N);
    k_aggregate<128, 1><<<ablk, 256, 0, stream>>>(bufH, rowptr, colidx, ndst, b1, nullptr, xhi, xlo, N);
    k_gemm_mfma<128, 1><<<gblk, 256, 0, stream>>>(nullptr, xhi, xlo, wt2h, wt2l, nsrc, bufH, N);
    k_aggregate<128, 1><<<ablk, 256, 0, stream>>>(bufH, rowptr, colidx, ndst, b2, nullptr, xhi, xlo, N);
    k_gemm_mfma<64, 1><<<gblk, 256, 0, stream>>>(nullptr, xhi, xlo, wt3h, wt3l, nsrc, bufH, N);
    k_aggregate<64, 0><<<ablk, 256, 0, stream>>>(bufH, rowptr, colidx, ndst, b3, out, nullptr, nullptr, N);
}

// Round 8
// 789.973 us; speedup vs baseline: 1.5369x; 1.0513x over previous
//
#include <hip/hip_runtime.h>
#include <cmath>

typedef __attribute__((ext_vector_type(8))) short bf16x8;
typedef __attribute__((ext_vector_type(4))) float f32x4;

__device__ inline unsigned short f2bf_rne(float f) {
    unsigned int u = __float_as_uint(f);
    unsigned int r = (u + 0x7FFFu + ((u >> 16) & 1u)) >> 16;
    return (unsigned short)r;
}
__device__ inline float bf2f(unsigned short h) {
    return __uint_as_float(((unsigned int)h) << 16);
}

// ---------------- CSR build via two-level counting sort (R7) ----------------
// Replaces per-edge DEVICE atomics (k_pass1 155us: 20 G atomics/s fabric-bound,
// 106 MB write-through) with LDS atomics only. Buckets of 64 nodes, K=ceil(N/64).
// NOTE: packing (dlocal<<17|src) requires N <= 2^17 (N=100000 here).

constexpr int CB = 256;   // counting-sort blocks

// A: per-block LDS histograms over coarse buckets, for dst and src
__global__ __launch_bounds__(256) void k_bucket_hist(const int* __restrict__ src,
                                                     const int* __restrict__ dst,
                                                     int* __restrict__ gHd, int* __restrict__ gHs,
                                                     int E, int K, int chunk) {
    extern __shared__ int lds[];
    int* hd = lds; int* hs = lds + K;
    for (int i = threadIdx.x; i < 2 * K; i += 256) lds[i] = 0;
    __syncthreads();
    int lo = blockIdx.x * chunk;
    int hi = lo + chunk; if (hi > E) hi = E;
    for (int i = lo + threadIdx.x; i < hi; i += 256) {
        atomicAdd(&hd[dst[i] >> 6], 1);
        atomicAdd(&hs[src[i] >> 6], 1);
    }
    __syncthreads();
    for (int k = threadIdx.x; k < K; k += 256) {
        gHd[(size_t)k * CB + blockIdx.x] = hd[k];
        gHs[(size_t)k * CB + blockIdx.x] = hs[k];
    }
}

// B: scatter edges into bucket-sorted arrays; position via LDS atomic on the
// preloaded scan-base column (no device atomics).
__global__ __launch_bounds__(256) void k_bucket_scatter(const int* __restrict__ src,
                                                        const int* __restrict__ dst,
                                                        const int* __restrict__ gHdS,
                                                        const int* __restrict__ gHsS,
                                                        int* __restrict__ sortedD,
                                                        int* __restrict__ sortedS,
                                                        int E, int K, int chunk) {
    extern __shared__ int lds[];
    int* bd = lds; int* bs = lds + K;
    for (int k = threadIdx.x; k < K; k += 256) {
        bd[k] = gHdS[(size_t)k * CB + blockIdx.x];
        bs[k] = gHsS[(size_t)k * CB + blockIdx.x];
    }
    __syncthreads();
    int lo = blockIdx.x * chunk;
    int hi = lo + chunk; if (hi > E) hi = E;
    for (int i = lo + threadIdx.x; i < hi; i += 256) {
        int d = dst[i], s = src[i];
        int pd = atomicAdd(&bd[d >> 6], 1);
        sortedD[pd] = ((d & 63) << 17) | s;
        int ps = atomicAdd(&bs[s >> 6], 1);
        sortedS[ps] = s;
    }
}

// C: per dst-bucket fine pass -> indeg, rowptr, colidx
__global__ __launch_bounds__(256) void k_fine_dst(const int* __restrict__ sortedD,
                                                  const int* __restrict__ gHdS,
                                                  int* __restrict__ rowptr,
                                                  int* __restrict__ indeg,
                                                  int* __restrict__ colidx,
                                                  int E, int K, int N) {
    __shared__ int cnt[64], excl[64], rank[64];
    int k = blockIdx.x;
    int bstart = gHdS[(size_t)k * CB];
    int bend = (k + 1 < K) ? gHdS[(size_t)(k + 1) * CB] : E;
    if (threadIdx.x < 64) { cnt[threadIdx.x] = 0; rank[threadIdx.x] = 0; }
    __syncthreads();
    for (int i = bstart + threadIdx.x; i < bend; i += 256)
        atomicAdd(&cnt[sortedD[i] >> 17], 1);
    __syncthreads();
    if (threadIdx.x == 0) {
        int r = 0;
        for (int j = 0; j < 64; j++) { excl[j] = r; r += cnt[j]; }
    }
    __syncthreads();
    int node0 = k << 6;
    if (threadIdx.x < 64) {
        int node = node0 + threadIdx.x;
        if (node < N) {
            rowptr[node] = bstart + excl[threadIdx.x];
            indeg[node] = cnt[threadIdx.x];
        }
    }
    if (k == 0 && threadIdx.x == 0) rowptr[N] = E;
    for (int i = bstart + threadIdx.x; i < bend; i += 256) {
        int v = sortedD[i];
        int n = v >> 17;
        int r = atomicAdd(&rank[n], 1);
        colidx[bstart + excl[n] + r] = v & 0x1FFFF;
    }
}

// C2: per src-bucket fine histogram -> outd
__global__ __launch_bounds__(256) void k_fine_src(const int* __restrict__ sortedS,
                                                  const int* __restrict__ gHsS,
                                                  int* __restrict__ outd,
                                                  int E, int K, int N) {
    __shared__ int cnt[64];
    int k = blockIdx.x;
    int bstart = gHsS[(size_t)k * CB];
    int bend = (k + 1 < K) ? gHsS[(size_t)(k + 1) * CB] : E;
    if (threadIdx.x < 64) cnt[threadIdx.x] = 0;
    __syncthreads();
    for (int i = bstart + threadIdx.x; i < bend; i += 256)
        atomicAdd(&cnt[sortedS[i] & 63], 1);
    __syncthreads();
    int node = (k << 6) + threadIdx.x;
    if (threadIdx.x < 64 && node < N) outd[node] = cnt[threadIdx.x];
}

__global__ void k_norms(const int* __restrict__ outd, const int* __restrict__ ind,
                        float* __restrict__ nsrc, float* __restrict__ ndst, int n) {
    int i = blockIdx.x * blockDim.x + threadIdx.x;
    if (i < n) {
        int od = outd[i], id = ind[i];
        nsrc[i] = od > 0 ? rsqrtf((float)od) : 0.f;
        ndst[i] = id > 0 ? rsqrtf((float)id) : 0.f;
    }
}

// W (fp32, k-major [k][n]) -> Wt hi/lo (bf16, n-major [n][k]), all 4 layers
__global__ void k_prepW_all(const float* __restrict__ W0, const float* __restrict__ W1,
                            const float* __restrict__ W2, const float* __restrict__ W3,
                            unsigned short* __restrict__ h0, unsigned short* __restrict__ l0,
                            unsigned short* __restrict__ h1, unsigned short* __restrict__ l1,
                            unsigned short* __restrict__ h2, unsigned short* __restrict__ l2,
                            unsigned short* __restrict__ h3, unsigned short* __restrict__ l3) {
    int i = blockIdx.x * 256 + threadIdx.x;
    const float* W; unsigned short* wh; unsigned short* wl; int N; int base;
    if      (i < 16384) { W = W0; wh = h0; wl = l0; N = 128; base = i; }
    else if (i < 32768) { W = W1; wh = h1; wl = l1; N = 128; base = i - 16384; }
    else if (i < 49152) { W = W2; wh = h2; wl = l2; N = 128; base = i - 32768; }
    else if (i < 57344) { W = W3; wh = h3; wl = l3; N = 64;  base = i - 49152; }
    else return;
    int n = base >> 7, k = base & 127;
    float w = W[k * N + n];
    unsigned short hb = f2bf_rne(w);
    unsigned short lb = f2bf_rne(w - bf2f(hb));
    wh[base] = hb; wl[base] = lb;
}

// ---------------- device-wide exclusive scan (tile = 2048) ----------------

constexpr int SCAN_TILE = 2048;

__global__ __launch_bounds__(256) void k_scan_partial(const int* __restrict__ deg,
                                                      int* __restrict__ tilesum, int n) {
    __shared__ int red[256];
    int base = blockIdx.x * SCAN_TILE;
    int s = 0;
    for (int i = threadIdx.x; i < SCAN_TILE; i += 256) {
        int idx = base + i;
        if (idx < n) s += deg[idx];
    }
    red[threadIdx.x] = s;
    __syncthreads();
    for (int off = 128; off > 0; off >>= 1) {
        if (threadIdx.x < off) red[threadIdx.x] += red[threadIdx.x + off];
        __syncthreads();
    }
    if (threadIdx.x == 0) tilesum[blockIdx.x] = red[0];
}

__global__ void k_scan_tiles(int* __restrict__ tilesum, int* __restrict__ outArr,
                             int numTiles, int n) {
    if (threadIdx.x == 0 && blockIdx.x == 0) {
        int acc = 0;
        for (int i = 0; i < numTiles; i++) { int v = tilesum[i]; tilesum[i] = acc; acc += v; }
        outArr[n] = acc;
    }
}

__global__ __launch_bounds__(256) void k_scan_final(const int* __restrict__ deg,
                                                    const int* __restrict__ tilesum,
                                                    int* __restrict__ outArr, int n) {
    __shared__ int red[256];
    int base = blockIdx.x * SCAN_TILE;
    int lo = base + threadIdx.x * 8;
    int v[8]; int s = 0;
#pragma unroll
    for (int j = 0; j < 8; j++) {
        int idx = lo + j;
        v[j] = (idx < n) ? deg[idx] : 0;
        s += v[j];
    }
    red[threadIdx.x] = s;
    __syncthreads();
    for (int off = 1; off < 256; off <<= 1) {
        int x = red[threadIdx.x];
        int add = (threadIdx.x >= off) ? red[threadIdx.x - off] : 0;
        __syncthreads();
        red[threadIdx.x] = x + add;
        __syncthreads();
    }
    int excl = tilesum[blockIdx.x] + (threadIdx.x ? red[threadIdx.x - 1] : 0);
#pragma unroll
    for (int j = 0; j < 8; j++) {
        int idx = lo + j;
        if (idx < n) outArr[idx] = excl;
        excl += v[j];
    }
}

// ---------------- GEMM via split-bf16 MFMA (R6, unchanged) ----------------

template <int DOUT, int SRC>
__global__ __launch_bounds__(256) void k_gemm_mfma(
        const float* __restrict__ xf,
        const unsigned short* __restrict__ xhi, const unsigned short* __restrict__ xlo,
        const unsigned short* __restrict__ wth, const unsigned short* __restrict__ wtl,
        const float* __restrict__ nsrc, float* __restrict__ h, int nrows) {
    constexpr int NP = DOUT / 64;
    constexpr int LDK = 72;
    __shared__ unsigned short Ah[64 * LDK], Al[64 * LDK];
    __shared__ unsigned short Bh[DOUT * LDK], Bl[DOUT * LDK];
    __shared__ float ns[64];

    int tid = threadIdx.x;
    int row0 = blockIdx.x * 64;
    int lane = tid & 63;
    int wv = tid >> 6;
    int quad = lane >> 4, l16 = lane & 15;

    if (tid < 64) {
        int row = row0 + tid; if (row >= nrows) row = nrows - 1;
        ns[tid] = nsrc[row];
    }

    f32x4 acc[4][NP];
#pragma unroll
    for (int mp = 0; mp < 4; mp++)
#pragma unroll
        for (int npi = 0; npi < NP; npi++)
            acc[mp][npi] = (f32x4){0.f, 0.f, 0.f, 0.f};

    for (int kh = 0; kh < 2; kh++) {
        if (kh) __syncthreads();
        for (int i = tid; i < 64 * 16; i += 256) {
            int r = i >> 4, kb = i & 15;
            int row = row0 + r; if (row >= nrows) row = nrows - 1;
            int koff = kh * 64 + kb * 4;
            if (SRC == 0) {
                float4 xv = *(const float4*)&xf[(size_t)row * 128 + koff];
                ushort4 hv, lv;
                hv.x = f2bf_rne(xv.x); lv.x = f2bf_rne(xv.x - bf2f(hv.x));
                hv.y = f2bf_rne(xv.y); lv.y = f2bf_rne(xv.y - bf2f(hv.y));
                hv.z = f2bf_rne(xv.z); lv.z = f2bf_rne(xv.z - bf2f(hv.z));
                hv.w = f2bf_rne(xv.w); lv.w = f2bf_rne(xv.w - bf2f(hv.w));
                *(ushort4*)&Ah[r * LDK + kb * 4] = hv;
                *(ushort4*)&Al[r * LDK + kb * 4] = lv;
            } else {
                *(ushort4*)&Ah[r * LDK + kb * 4] = *(const ushort4*)&xhi[(size_t)row * 128 + koff];
                *(ushort4*)&Al[r * LDK + kb * 4] = *(const ushort4*)&xlo[(size_t)row * 128 + koff];
            }
        }
        for (int i = tid; i < DOUT * 16; i += 256) {
            int n = i >> 4, kb = i & 15;
            int koff = kh * 64 + kb * 4;
            *(ushort4*)&Bh[n * LDK + kb * 4] = *(const ushort4*)&wth[n * 128 + koff];
            *(ushort4*)&Bl[n * LDK + kb * 4] = *(const ushort4*)&wtl[n * 128 + koff];
        }
        __syncthreads();

        for (int kq = 0; kq < 2; kq++) {
            int ko = kq * 32 + quad * 8;
            bf16x8 ah[4], al[4], bh[NP], bl[NP];
#pragma unroll
            for (int mp = 0; mp < 4; mp++) {
                ah[mp] = *(const bf16x8*)&Ah[(mp * 16 + l16) * LDK + ko];
                al[mp] = *(const bf16x8*)&Al[(mp * 16 + l16) * LDK + ko];
            }
#pragma unroll
            for (int npi = 0; npi < NP; npi++) {
                int n = (wv * NP + npi) * 16 + l16;
                bh[npi] = *(const bf16x8*)&Bh[n * LDK + ko];
                bl[npi] = *(const bf16x8*)&Bl[n * LDK + ko];
            }
#pragma unroll
            for (int mp = 0; mp < 4; mp++)
#pragma unroll
                for (int npi = 0; npi < NP; npi++) {
                    acc[mp][npi] = __builtin_amdgcn_mfma_f32_16x16x32_bf16(ah[mp], bh[npi], acc[mp][npi], 0, 0, 0);
                    acc[mp][npi] = __builtin_amdgcn_mfma_f32_16x16x32_bf16(ah[mp], bl[npi], acc[mp][npi], 0, 0, 0);
                    acc[mp][npi] = __builtin_amdgcn_mfma_f32_16x16x32_bf16(al[mp], bh[npi], acc[mp][npi], 0, 0, 0);
                }
        }
    }

#pragma unroll
    for (int mp = 0; mp < 4; mp++) {
#pragma unroll
        for (int r = 0; r < 4; r++) {
            int rl = mp * 16 + quad * 4 + r;
            int row = row0 + rl;
            if (row < nrows) {
                float nm = ns[rl];
#pragma unroll
                for (int npi = 0; npi < NP; npi++) {
                    int col = (wv * NP + npi) * 16 + l16;
                    h[(size_t)row * DOUT + col] = acc[mp][npi][r] * nm;
                }
            }
        }
    }
}

// ---------------- aggregation: wave-per-node, MLP=8 (R6, unchanged) ----------------

template <int D, int MODE>
__global__ __launch_bounds__(256) void k_aggregate(const float* __restrict__ h,
                                                   const int* __restrict__ rowptr,
                                                   const int* __restrict__ colidx,
                                                   const float* __restrict__ ndst,
                                                   const float* __restrict__ bias,
                                                   float* __restrict__ out,
                                                   unsigned short* __restrict__ ohi,
                                                   unsigned short* __restrict__ olo,
                                                   int n) {
    constexpr int FB = D / 4;
    constexpr int G  = 64 / FB;
    constexpr int U  = 8;
    constexpr int UG = U * G;
    int wid  = (blockIdx.x * 256 + threadIdx.x) >> 6;
    int lane = threadIdx.x & 63;
    int fb = lane & (FB - 1);
    int g  = lane / FB;
    int waveCount = gridDim.x * 4;
    const float4* h4 = (const float4*)h;

    for (int node = wid; node < n; node += waveCount) {
        int beg = rowptr[node], end = rowptr[node + 1];
        float4 a0 = {0, 0, 0, 0}, a1 = {0, 0, 0, 0}, a2 = {0, 0, 0, 0}, a3 = {0, 0, 0, 0};

        for (int base = beg; base < end; base += 64) {
            int m = end - base; if (m > 64) m = 64;
            int cv = colidx[base + (lane < m ? lane : 0)];
            int nb = (m + UG - 1) / UG;       // wave-uniform trip count
            for (int b = 0; b < nb; b++) {
                int s[U]; float w[U];
#pragma unroll
                for (int u = 0; u < U; u++) {
                    int j = b * UG + u * G + g;
                    int q = j < m ? j : 0;
                    w[u] = j < m ? 1.f : 0.f;
                    s[u] = __shfl(cv, q);
                }
                float4 v[U];
#pragma unroll
                for (int u = 0; u < U; u++)
                    v[u] = h4[(size_t)s[u] * FB + fb];
#pragma unroll
                for (int u = 0; u < U; u += 4) {
                    a0.x = fmaf(v[u].x, w[u], a0.x); a0.y = fmaf(v[u].y, w[u], a0.y);
                    a0.z = fmaf(v[u].z, w[u], a0.z); a0.w = fmaf(v[u].w, w[u], a0.w);
                    a1.x = fmaf(v[u+1].x, w[u+1], a1.x); a1.y = fmaf(v[u+1].y, w[u+1], a1.y);
                    a1.z = fmaf(v[u+1].z, w[u+1], a1.z); a1.w = fmaf(v[u+1].w, w[u+1], a1.w);
                    a2.x = fmaf(v[u+2].x, w[u+2], a2.x); a2.y = fmaf(v[u+2].y, w[u+2], a2.y);
                    a2.z = fmaf(v[u+2].z, w[u+2], a2.z); a2.w = fmaf(v[u+2].w, w[u+2], a2.w);
                    a3.x = fmaf(v[u+3].x, w[u+3], a3.x); a3.y = fmaf(v[u+3].y, w[u+3], a3.y);
                    a3.z = fmaf(v[u+3].z, w[u+3], a3.z); a3.w = fmaf(v[u+3].w, w[u+3], a3.w);
                }
            }
        }

        float4 acc;
        acc.x = (a0.x + a1.x) + (a2.x + a3.x);
        acc.y = (a0.y + a1.y) + (a2.y + a3.y);
        acc.z = (a0.z + a1.z) + (a2.z + a3.z);
        acc.w = (a0.w + a1.w) + (a2.w + a3.w);
#pragma unroll
        for (int off = FB; off < 64; off <<= 1) {
            acc.x += __shfl_xor(acc.x, off);
            acc.y += __shfl_xor(acc.y, off);
            acc.z += __shfl_xor(acc.z, off);
            acc.w += __shfl_xor(acc.w, off);
        }
        if (g == 0) {
            float nd = ndst[node];
            float4 bv = ((const float4*)bias)[fb];
            float4 v;
            v.x = acc.x * nd + bv.x;
            v.y = acc.y * nd + bv.y;
            v.z = acc.z * nd + bv.z;
            v.w = acc.w * nd + bv.w;
            if (MODE == 1) {
                v.x = tanhf(v.x); v.y = tanhf(v.y);
                v.z = tanhf(v.z); v.w = tanhf(v.w);
                ushort4 hv, lv;
                hv.x = f2bf_rne(v.x); lv.x = f2bf_rne(v.x - bf2f(hv.x));
                hv.y = f2bf_rne(v.y); lv.y = f2bf_rne(v.y - bf2f(hv.y));
                hv.z = f2bf_rne(v.z); lv.z = f2bf_rne(v.z - bf2f(hv.z));
                hv.w = f2bf_rne(v.w); lv.w = f2bf_rne(v.w - bf2f(hv.w));
                *(ushort4*)&ohi[(size_t)node * D + fb * 4] = hv;
                *(ushort4*)&olo[(size_t)node * D + fb * 4] = lv;
            } else {
                ((float4*)out)[(size_t)node * FB + fb] = v;
            }
        }
    }
}

// ---------------- host ----------------

extern "C" void kernel_launch(void* const* d_in, const int* in_sizes, int n_in,
                              void* d_out, int out_size, void* d_ws, size_t ws_size,
                              hipStream_t stream) {
    const float* features = (const float*)d_in[0];
    const int* edges      = (const int*)d_in[1];
    const float* W0 = (const float*)d_in[2]; const float* b0 = (const float*)d_in[3];
    const float* W1 = (const float*)d_in[4]; const float* b1 = (const float*)d_in[5];
    const float* W2 = (const float*)d_in[6]; const float* b2 = (const float*)d_in[7];
    const float* W3 = (const float*)d_in[8]; const float* b3 = (const float*)d_in[9];
    float* out = (float*)d_out;

    const int N = in_sizes[0] / 128;
    const int E = in_sizes[1] / 2;
    const int* src = edges;
    const int* dst = edges + E;
    const int K = (N + 63) >> 6;                  // coarse buckets (64 nodes each)
    const int chunk = (E + CB - 1) / CB;
    const int scanN = K * CB;
    const int numTiles = (scanN + SCAN_TILE - 1) / SCAN_TILE;
    const size_t dynLds = (size_t)2 * K * sizeof(int);

    char* p = (char*)d_ws;
    float* bufH            = (float*)p;          p += (size_t)N * 128 * 4;
    unsigned short* xhi    = (unsigned short*)p; p += (size_t)N * 128 * 2;
    unsigned short* xlo    = (unsigned short*)p; p += (size_t)N * 128 * 2;
    int*   rowptr = (int*)p;   p += (((size_t)(N + 1) * 4 + 15) / 16) * 16;
    int*   colidx = (int*)p;   p += (size_t)E * 4;
    int*   outd   = (int*)p;   p += (size_t)N * 4;
    int*   indeg  = (int*)p;   p += (size_t)N * 4;
    float* nsrc   = (float*)p; p += (size_t)N * 4;
    float* ndst   = (float*)p; p += (size_t)N * 4;
    int*   tilesum= (int*)p;   p += (((size_t)(numTiles + 1) * 4 + 15) / 16) * 16;
    unsigned short* wt0h = (unsigned short*)p; p += 16384 * 2;
    unsigned short* wt0l = (unsigned short*)p; p += 16384 * 2;
    unsigned short* wt1h = (unsigned short*)p; p += 16384 * 2;
    unsigned short* wt1l = (unsigned short*)p; p += 16384 * 2;
    unsigned short* wt2h = (unsigned short*)p; p += 16384 * 2;
    unsigned short* wt2l = (unsigned short*)p; p += 16384 * 2;
    unsigned short* wt3h = (unsigned short*)p; p += 8192 * 2;
    unsigned short* wt3l = (unsigned short*)p; p += 8192 * 2;

    // transient counting-sort buffers aliased into xhi/xlo region (51.2 MB;
    // xhi/xlo first written by aggregate L0, long after k_fine_* complete)
    char* q = (char*)xhi;
    int* sortedD = (int*)q; q += (size_t)E * 4;
    int* sortedS = (int*)q; q += (size_t)E * 4;
    int* gHd     = (int*)q; q += (size_t)scanN * 4;
    int* gHs     = (int*)q; q += (size_t)scanN * 4;
    int* gHdS    = (int*)q; q += (size_t)(scanN + 1) * 4;
    int* gHsS    = (int*)q; q += (size_t)(scanN + 1) * 4;

    k_prepW_all<<<224, 256, 0, stream>>>(W0, W1, W2, W3, wt0h, wt0l, wt1h, wt1l,
                                         wt2h, wt2l, wt3h, wt3l);
    k_bucket_hist<<<CB, 256, dynLds, stream>>>(src, dst, gHd, gHs, E, K, chunk);
    k_scan_partial<<<numTiles, 256, 0, stream>>>(gHd, tilesum, scanN);
    k_scan_tiles<<<1, 64, 0, stream>>>(tilesum, gHdS, numTiles, scanN);
    k_scan_final<<<numTiles, 256, 0, stream>>>(gHd, tilesum, gHdS, scanN);
    k_scan_partial<<<numTiles, 256, 0, stream>>>(gHs, tilesum, scanN);
    k_scan_tiles<<<1, 64, 0, stream>>>(tilesum, gHsS, numTiles, scanN);
    k_scan_final<<<numTiles, 256, 0, stream>>>(gHs, tilesum, gHsS, scanN);
    k_bucket_scatter<<<CB, 256, dynLds, stream>>>(src, dst, gHdS, gHsS, sortedD, sortedS, E, K, chunk);
    k_fine_dst<<<K, 256, 0, stream>>>(sortedD, gHdS, rowptr, indeg, colidx, E, K, N);
    k_fine_src<<<K, 256, 0, stream>>>(sortedS, gHsS, outd, E, K, N);
    k_norms<<<(N + 255) / 256, 256, 0, stream>>>(outd, indeg, nsrc, ndst, N);

    int gblk = (N + 63) / 64;
    int ablk = 4096;
    k_gemm_mfma<128, 0><<<gblk, 256, 0, stream>>>(features, nullptr, nullptr, wt0h, wt0l, nsrc, bufH, N);
    k_aggregate<128, 1><<<ablk, 256, 0, stream>>>(bufH, rowptr, colidx, ndst, b0, nullptr, xhi, xlo, N);
    k_gemm_mfma<128, 1><<<gblk, 256, 0, stream>>>(nullptr, xhi, xlo, wt1h, wt1l, nsrc, bufH, N);
    k_aggregate<128, 1><<<ablk, 256, 0, stream>>>(bufH, rowptr, colidx, ndst, b1, nullptr, xhi, xlo, N);
    k_gemm_mfma<128, 1><<<gblk, 256, 0, stream>>>(nullptr, xhi, xlo, wt2h, wt2l, nsrc, bufH, N);
    k_aggregate<128, 1><<<ablk, 256, 0, stream>>>(bufH, rowptr, colidx, ndst, b2, nullptr, xhi, xlo, N);
    k_gemm_mfma<64, 1><<<gblk, 256, 0, stream>>>(nullptr, xhi, xlo, wt3h, wt3l, nsrc, bufH, N);
    k_aggregate<64, 0><<<ablk, 256, 0, stream>>>(bufH, rowptr, colidx, ndst, b3, out, nullptr, nullptr, N);
}